// Round 2
// baseline (2507.543 us; speedup 1.0000x reference)
//
#include <hip/hip_runtime.h>
#include <hip/hip_bf16.h>
#include <stdint.h>

typedef __attribute__((ext_vector_type(4))) float f32x4;
typedef __attribute__((ext_vector_type(8))) short bf16x8;
typedef __attribute__((ext_vector_type(4))) unsigned short us4;
typedef __attribute__((ext_vector_type(8))) unsigned short us8;

static constexpr int Bb = 8, Ss = 2048, Dd = 1024, Hh = 16, DHh = 64;
static constexpr int Mm = Bb * Ss;   // 16384
#define DEVI static __device__ __forceinline__

DEVI float bf2f(unsigned short u) {
  union { unsigned int i; float f; } v; v.i = ((unsigned int)u) << 16; return v.f;
}
DEVI unsigned short f2bf(float f) {
  union { float f; unsigned int i; } v; v.f = f;
  unsigned int r = v.i + 0x7FFFu + ((v.i >> 16) & 1u);
  return (unsigned short)(r >> 16);
}

// ---- W [K=1024][N=1024] f32 -> WT bf16 [N][K] ----
__global__ __launch_bounds__(256) void k_transpose_w(const float* __restrict__ W,
                                                     unsigned short* __restrict__ WT) {
  __shared__ float tile[32][33];
  const int n0 = blockIdx.x * 32, k0 = blockIdx.y * 32;
  const int t = threadIdx.x, tr = t >> 5, tc = t & 31;
#pragma unroll
  for (int i = 0; i < 4; i++) {
    int r = tr + 8 * i;
    tile[r][tc] = W[(size_t)(k0 + r) * 1024 + n0 + tc];
  }
  __syncthreads();
#pragma unroll
  for (int i = 0; i < 4; i++) {
    int r = tr + 8 * i;
    WT[(size_t)(n0 + r) * 1024 + k0 + tc] = f2bf(tile[tc][r]);
  }
}

// ---- f32 -> bf16 elementwise ----
__global__ __launch_bounds__(256) void k_cvt(const float* __restrict__ x,
                                             unsigned short* __restrict__ y) {
  const int n4 = (Mm * Dd) / 4;
  for (int i = blockIdx.x * 256 + threadIdx.x; i < n4; i += gridDim.x * 256) {
    f32x4 v = ((const f32x4*)x)[i];
    us4 o = { f2bf(v.x), f2bf(v.y), f2bf(v.z), f2bf(v.w) };
    ((us4*)y)[i] = o;
  }
}

// ---- Qmid/Kmid = in[16384,1024] @ W1[1024,32] (f32) ----
__global__ __launch_bounds__(256) void k_qkmid(const float* __restrict__ inQ, const float* __restrict__ inK,
                                               const float* __restrict__ Wq1, const float* __restrict__ Wk1,
                                               float* __restrict__ Qmid, float* __restrict__ Kmid) {
  const float* in = blockIdx.y ? inK : inQ;
  const float* W  = blockIdx.y ? Wk1 : Wq1;
  float* outp     = blockIdx.y ? Kmid : Qmid;
  __shared__ float rows[8][1024];
  const int r0 = blockIdx.x * 8;
  const int t = threadIdx.x;
  const f32x4* src = (const f32x4*)(in + (size_t)r0 * 1024);
  f32x4* dstl = (f32x4*)rows;
#pragma unroll
  for (int i = 0; i < 8; i++) dstl[t + 256 * i] = src[t + 256 * i];
  __syncthreads();
  const int g = t >> 5, j = t & 31;
  float acc = 0.f;
#pragma unroll 8
  for (int k = 0; k < 1024; k++) acc += rows[g][k] * W[k * 32 + j];
  outp[(size_t)(r0 + g) * 32 + j] = acc;
}

// ---- Q/K = mid[16384,32] @ W2[32,1024] -> bf16 [b,h,s,f] ----
__global__ __launch_bounds__(256) void k_qkexpand(const float* __restrict__ Qmid, const float* __restrict__ Kmid,
                                                  const float* __restrict__ Wq2, const float* __restrict__ Wk2,
                                                  unsigned short* __restrict__ Qp, unsigned short* __restrict__ Kp) {
  const float* mid = blockIdx.y ? Kmid : Qmid;
  const float* W   = blockIdx.y ? Wk2 : Wq2;
  unsigned short* outp = blockIdx.y ? Kp : Qp;
  __shared__ float sv[16][32];
  const int r0 = blockIdx.x * 16;
  const int t = threadIdx.x;
  ((float*)sv)[t]       = mid[(size_t)r0 * 32 + t];
  ((float*)sv)[t + 256] = mid[(size_t)r0 * 32 + t + 256];
  __syncthreads();
  const int c0 = t * 4;
  f32x4 acc[16];
#pragma unroll
  for (int ri = 0; ri < 16; ri++) acc[ri] = (f32x4){0.f, 0.f, 0.f, 0.f};
#pragma unroll
  for (int k = 0; k < 32; k++) {
    f32x4 w = *(const f32x4*)&W[k * 1024 + c0];
#pragma unroll
    for (int ri = 0; ri < 16; ri++) acc[ri] += sv[ri][k] * w;
  }
  const int h = c0 >> 6, f = c0 & 63;
#pragma unroll
  for (int ri = 0; ri < 16; ri++) {
    int r = r0 + ri;
    int b = r >> 11, s = r & 2047;
    us4 o = { f2bf(acc[ri].x), f2bf(acc[ri].y), f2bf(acc[ri].z), f2bf(acc[ri].w) };
    *(us4*)&outp[(((size_t)(b * 16 + h) * 2048) + s) * 64 + f] = o;
  }
}

// ---- per-(b,h) transpose: [2048][64] bf16 -> [64][2048] bf16 ----
__global__ __launch_bounds__(256) void k_transpose_bh(const unsigned short* __restrict__ src,
                                                      unsigned short* __restrict__ dst) {
  __shared__ unsigned short tile[64][72];
  const int bh = blockIdx.y, s0 = blockIdx.x * 64;
  const int t = threadIdx.x;
  {
    int sl = t >> 2, fc = (t & 3) * 16;
    const unsigned short* sp = src + ((size_t)bh * 2048 + s0 + sl) * 64 + fc;
    *(us8*)&tile[sl][fc]     = *(const us8*)sp;
    *(us8*)&tile[sl][fc + 8] = *(const us8*)(sp + 8);
  }
  __syncthreads();
  {
    int f = t >> 2, sc = (t & 3) * 16;
    unsigned short* dp = dst + ((size_t)bh * 64 + f) * 2048 + s0 + sc;
    us8 a, bq;
#pragma unroll
    for (int i = 0; i < 8; i++) a[i] = tile[sc + i][f];
#pragma unroll
    for (int i = 0; i < 8; i++) bq[i] = tile[sc + 8 + i][f];
    *(us8*)dp = a;
    *(us8*)(dp + 8) = bq;
  }
}

// ---- bf16 MFMA GEMM: A[M,1024] bf16 @ (BT[N,1024])^T, 128x128 tile, BK=64 ----
// EPI 0: write bf16 to [b,h,s,f] layout (V projection). EPI 1: write f32 row-major.
template <int EPI>
__global__ __launch_bounds__(256) void k_gemm(const unsigned short* __restrict__ Ag,
                                              const unsigned short* __restrict__ BTg,
                                              void* __restrict__ Cout) {
  __shared__ unsigned short As[128 * 64];
  __shared__ unsigned short Bs[128 * 64];
  const int m0 = blockIdx.y * 128, n0 = blockIdx.x * 128;
  const int t = threadIdx.x;
  const int w = t >> 6, l = t & 63;
  const int wr = w >> 1, wc = w & 1;
  const int g4 = l >> 4, l16 = l & 15;
  f32x4 acc[4][4];
#pragma unroll
  for (int i = 0; i < 4; i++)
#pragma unroll
    for (int jj = 0; jj < 4; jj++) acc[i][jj] = (f32x4){0.f, 0.f, 0.f, 0.f};

  const int srow = t >> 1, shalf = (t & 1) * 32;
  const us8* ga = (const us8*)(Ag  + (size_t)(m0 + srow) * 1024 + shalf);
  const us8* gb = (const us8*)(BTg + (size_t)(n0 + srow) * 1024 + shalf);
  const int swz = (srow & 7) << 4;
#pragma unroll 1
  for (int kt = 0; kt < 16; kt++) {
    __syncthreads();
#pragma unroll
    for (int c = 0; c < 4; c++) {
      int kb = (shalf + c * 8) * 2;
      *(us8*)&As[srow * 64 + ((kb ^ swz) >> 1)] = ga[c];
      *(us8*)&Bs[srow * 64 + ((kb ^ swz) >> 1)] = gb[c];
    }
    ga += 8; gb += 8;
    __syncthreads();
#pragma unroll
    for (int kk = 0; kk < 64; kk += 32) {
      bf16x8 af[4], bfr[4];
      const int kbyte = (kk + 8 * g4) * 2;
#pragma unroll
      for (int mt = 0; mt < 4; mt++) {
        int row = wr * 64 + mt * 16 + l16;
        af[mt] = *(const bf16x8*)&As[row * 64 + ((kbyte ^ ((row & 7) << 4)) >> 1)];
      }
#pragma unroll
      for (int nt = 0; nt < 4; nt++) {
        int row = wc * 64 + nt * 16 + l16;
        bfr[nt] = *(const bf16x8*)&Bs[row * 64 + ((kbyte ^ ((row & 7) << 4)) >> 1)];
      }
#pragma unroll
      for (int mt = 0; mt < 4; mt++)
#pragma unroll
        for (int nt = 0; nt < 4; nt++)
          acc[mt][nt] = __builtin_amdgcn_mfma_f32_16x16x32_bf16(af[mt], bfr[nt], acc[mt][nt], 0, 0, 0);
    }
  }
#pragma unroll
  for (int mt = 0; mt < 4; mt++)
#pragma unroll
    for (int nt = 0; nt < 4; nt++)
#pragma unroll
      for (int r = 0; r < 4; r++) {
        int m = m0 + wr * 64 + mt * 16 + g4 * 4 + r;
        int n = n0 + wc * 64 + nt * 16 + l16;
        float v = acc[mt][nt][r];
        if (EPI == 0) {
          int b = m >> 11, s = m & 2047, h = n >> 6, f = n & 63;
          ((unsigned short*)Cout)[(((size_t)(b * 16 + h) * 2048) + s) * 64 + f] = f2bf(v);
        } else {
          ((float*)Cout)[(size_t)m * 1024 + n] = v;
        }
      }
}

// ---- stage 1: scores = 0.125*A^T K^T, softmax over s (2048), attn->d_out, VVn = attn@V (normalized)
// grid (4, 128): block = 16 waves, wave w owns d = dblk*16+w; lanes sweep s.
__global__ __launch_bounds__(1024) void k_stage1(const unsigned short* __restrict__ KpT,
                                                 const unsigned short* __restrict__ VpT,
                                                 const float* __restrict__ Aw,
                                                 float* __restrict__ attn_out, float* __restrict__ VVn) {
  __shared__ float Asub[64][16];
  __shared__ float Kt[64][64];
  __shared__ float Vt[64][64];
  const int bh = blockIdx.y, dblk = blockIdx.x;
  const int t = threadIdx.x;
  const int wv = t >> 6, l = t & 63;
  const int d = dblk * 16 + wv;
  {
    int f = t >> 4, dl = t & 15;
    Asub[f][dl] = Aw[f * 64 + dblk * 16 + dl];
  }
  const unsigned short* kbase = KpT + (size_t)bh * 64 * 2048;
  const unsigned short* vbase = VpT + (size_t)bh * 64 * 2048;
  const int sf = t >> 4, s4 = (t & 15) * 4;
  float m = -1e30f, lsum = 0.f;
  for (int st = 0; st < 32; st++) {
    __syncthreads();
    {
      us4 kv = *(const us4*)&kbase[(size_t)sf * 2048 + st * 64 + s4];
      f32x4 kf = { bf2f(kv.x), bf2f(kv.y), bf2f(kv.z), bf2f(kv.w) };
      *(f32x4*)&Kt[sf][s4] = kf;
    }
    __syncthreads();
    float sc = 0.f;
#pragma unroll 16
    for (int f = 0; f < 64; f++) sc += Asub[f][wv] * Kt[f][l];
    sc *= 0.125f;
    float nm = fmaxf(m, sc);
    lsum = lsum * __expf(m - nm) + __expf(sc - nm);
    m = nm;
  }
#pragma unroll
  for (int o = 1; o < 64; o <<= 1) {
    float m2 = __shfl_xor(m, o);
    float l2 = __shfl_xor(lsum, o);
    float nm = fmaxf(m, m2);
    lsum = lsum * __expf(m - nm) + l2 * __expf(m2 - nm);
    m = nm;
  }
  const float invl = 1.f / lsum;
  float vvp[64];
#pragma unroll
  for (int f = 0; f < 64; f++) vvp[f] = 0.f;
  float* aout = attn_out + ((size_t)bh * 64 + d) * 2048;
  for (int st = 0; st < 32; st++) {
    __syncthreads();
    {
      us4 kv = *(const us4*)&kbase[(size_t)sf * 2048 + st * 64 + s4];
      us4 vq = *(const us4*)&vbase[(size_t)sf * 2048 + st * 64 + s4];
      f32x4 kf = { bf2f(kv.x), bf2f(kv.y), bf2f(kv.z), bf2f(kv.w) };
      f32x4 vf = { bf2f(vq.x), bf2f(vq.y), bf2f(vq.z), bf2f(vq.w) };
      *(f32x4*)&Kt[sf][s4] = kf;
      *(f32x4*)&Vt[sf][s4] = vf;
    }
    __syncthreads();
    float sc = 0.f;
#pragma unroll 16
    for (int f = 0; f < 64; f++) sc += Asub[f][wv] * Kt[f][l];
    float e = __expf(sc * 0.125f - m) * invl;
    aout[st * 64 + l] = e;
#pragma unroll 16
    for (int f = 0; f < 64; f++) vvp[f] += e * Vt[f][l];
  }
#pragma unroll
  for (int o = 1; o < 64; o <<= 1)
#pragma unroll
    for (int f = 0; f < 64; f++) vvp[f] += __shfl_xor(vvp[f], o);
  float myv = 0.f;
#pragma unroll
  for (int f = 0; f < 64; f++) if (l == f) myv = vvp[f];
  VVn[(((size_t)bh * 64) + d) * 64 + l] = myv;
}

// ---- stage 2: scores2 = 0.125*Q A^T, softmax over d (64), VVV = attn2@VV, scatter reshape into X
__global__ __launch_bounds__(256) void k_stage2(const unsigned short* __restrict__ Qp,
                                                const float* __restrict__ Aw,
                                                const float* __restrict__ VVn, float* __restrict__ X) {
  __shared__ float A2[64][65];
  __shared__ float VVl[64][65];
  __shared__ float Qt[64][64];
  __shared__ float At[4][64];
  const int bh = blockIdx.y, b = bh >> 4, h = bh & 15;
  const int s0 = blockIdx.x * 64;
  const int t = threadIdx.x;
  const int wv = t >> 6, l = t & 63;
  for (int i = t; i < 4096; i += 256) {
    int dd = i >> 6, ff = i & 63;
    A2[dd][ff]  = Aw[i];
    VVl[dd][ff] = VVn[(size_t)bh * 4096 + i];
  }
  {
    int sl = t >> 2, fc = (t & 3) * 16;
    const unsigned short* qp = Qp + ((size_t)bh * 2048 + s0 + sl) * 64 + fc;
#pragma unroll
    for (int u = 0; u < 4; u++) {
      us4 q = *(const us4*)(qp + u * 4);
      f32x4 qf = { bf2f(q.x), bf2f(q.y), bf2f(q.z), bf2f(q.w) };
      *(f32x4*)&Qt[sl][fc + u * 4] = qf;
    }
  }
  __syncthreads();
  for (int i = 0; i < 16; i++) {
    const int sl = i * 4 + wv;
    float sc = 0.f;
#pragma unroll 16
    for (int f = 0; f < 64; f++) sc += Qt[sl][f] * A2[l][f];
    sc *= 0.125f;
    float mx = sc;
#pragma unroll
    for (int o = 1; o < 64; o <<= 1) mx = fmaxf(mx, __shfl_xor(mx, o));
    float e = __expf(sc - mx);
    float sm = e;
#pragma unroll
    for (int o = 1; o < 64; o <<= 1) sm += __shfl_xor(sm, o);
    At[wv][l] = e / sm;
    __syncthreads();
    {
      float v = 0.f;
#pragma unroll 16
      for (int dd = 0; dd < 64; dd++) v += At[wv][dd] * VVl[dd][l];
      const int ss = s0 + sl;
      const int jj = h * 128 + (ss >> 4);
      const int cc = (ss & 15) * 64 + l;
      X[((size_t)(b * 2048 + jj)) * 1024 + cc] = v;
    }
    __syncthreads();
  }
}

// ---- residual + LayerNorm; optionally also write bf16 copy ----
template <bool WB>
__global__ __launch_bounds__(256) void k_ln(const float* __restrict__ xa, const float* __restrict__ xb,
                                            const float* __restrict__ g, const float* __restrict__ bbv,
                                            float* __restrict__ outf, unsigned short* __restrict__ outb) {
  __shared__ float red[2][4];
  const size_t row = blockIdx.x;
  const int t = threadIdx.x;
  const int wv = t >> 6, l = t & 63;
  f32x4 va = ((const f32x4*)(xa + row * 1024))[t];
  f32x4 vb = ((const f32x4*)(xb + row * 1024))[t];
  f32x4 v = va + vb;
  float s = v.x + v.y + v.z + v.w;
  float q = v.x * v.x + v.y * v.y + v.z * v.z + v.w * v.w;
#pragma unroll
  for (int o = 1; o < 64; o <<= 1) { s += __shfl_xor(s, o); q += __shfl_xor(q, o); }
  if (l == 0) { red[0][wv] = s; red[1][wv] = q; }
  __syncthreads();
  s = red[0][0] + red[0][1] + red[0][2] + red[0][3];
  q = red[1][0] + red[1][1] + red[1][2] + red[1][3];
  const float mean = s * (1.f / 1024.f);
  const float var = q * (1.f / 1024.f) - mean * mean;
  const float rstd = rsqrtf(var + 1e-5f);
  f32x4 gg = ((const f32x4*)g)[t];
  f32x4 bv = ((const f32x4*)bbv)[t];
  f32x4 o;
  o.x = (v.x - mean) * rstd * gg.x + bv.x;
  o.y = (v.y - mean) * rstd * gg.y + bv.y;
  o.z = (v.z - mean) * rstd * gg.z + bv.z;
  o.w = (v.w - mean) * rstd * gg.w + bv.w;
  ((f32x4*)(outf + row * 1024))[t] = o;
  if (WB) {
    us4 ob = { f2bf(o.x), f2bf(o.y), f2bf(o.z), f2bf(o.w) };
    ((us4*)(outb + row * 1024))[t] = ob;
  }
}

extern "C" void kernel_launch(void* const* d_in, const int* in_sizes, int n_in,
                              void* d_out, int out_size, void* d_ws, size_t ws_size,
                              hipStream_t stream) {
  const float* inQ = (const float*)d_in[0];
  const float* inK = (const float*)d_in[1];
  const float* inV = (const float*)d_in[2];
  const float* Wq1 = (const float*)d_in[3];
  const float* Wq2 = (const float*)d_in[4];
  const float* Wk1 = (const float*)d_in[5];
  const float* Wk2 = (const float*)d_in[6];
  const float* Wv  = (const float*)d_in[7];
  const float* Wfc = (const float*)d_in[8];
  const float* Aw  = (const float*)d_in[9];
  const float* lng = (const float*)d_in[10];
  const float* lnb = (const float*)d_in[11];
  float* out = (float*)d_out;
  float* attn_out = out + (size_t)Mm * Dd;   // output 1: attn_VV [8,16,64,2048]

  char* ws = (char*)d_ws;
  // layout (bytes); total 211,812,352 (~202 MiB), with lifetime-safe aliasing
  unsigned short* WvT  = (unsigned short*)(ws + 0ull);           //  2 MB
  unsigned short* WfcT = (unsigned short*)(ws + 2097152ull);     //  2 MB
  float* Qmid          = (float*)(ws + 4194304ull);              //  2 MB
  float* Kmid          = (float*)(ws + 6291456ull);              //  2 MB
  unsigned short* Qp   = (unsigned short*)(ws + 8388608ull);     // 32 MB
  unsigned short* Kp   = (unsigned short*)(ws + 41943040ull);    // 32 MB -> later o1 bf16
  unsigned short* KpT  = (unsigned short*)(ws + 75497472ull);    // 32 MB ┐-> later o2 (64 MB f32)
  unsigned short* VpT  = (unsigned short*)(ws + 109051904ull);   // 32 MB ┘
  unsigned short* Vbf  = (unsigned short*)(ws + 142606336ull);   // 32 MB ┐-> later X / o1f (64 MB f32)
  unsigned short* Vp   = (unsigned short*)(ws + 176160768ull);   // 32 MB ┘
  float* VVn           = (float*)(ws + 209715200ull);            //  2 MB
  float* o2  = (float*)(ws + 75497472ull);
  float* X   = (float*)(ws + 142606336ull);
  float* o1f = X;
  unsigned short* o1b = Kp;

  k_transpose_w<<<dim3(32, 32), 256, 0, stream>>>(Wv, WvT);
  k_transpose_w<<<dim3(32, 32), 256, 0, stream>>>(Wfc, WfcT);
  k_cvt<<<dim3(4096), 256, 0, stream>>>(inV, Vbf);
  k_qkmid<<<dim3(2048, 2), 256, 0, stream>>>(inQ, inK, Wq1, Wk1, Qmid, Kmid);
  k_qkexpand<<<dim3(1024, 2), 256, 0, stream>>>(Qmid, Kmid, Wq2, Wk2, Qp, Kp);
  k_transpose_bh<<<dim3(32, 128), 256, 0, stream>>>(Kp, KpT);
  k_gemm<0><<<dim3(8, 128), 256, 0, stream>>>(Vbf, WvT, (void*)Vp);
  k_transpose_bh<<<dim3(32, 128), 256, 0, stream>>>(Vp, VpT);
  k_stage1<<<dim3(4, 128), 1024, 0, stream>>>(KpT, VpT, Aw, attn_out, VVn);
  k_stage2<<<dim3(32, 128), 256, 0, stream>>>(Qp, Aw, VVn, X);
  k_ln<true><<<dim3(16384), 256, 0, stream>>>(X, inQ, lng, lnb, o1f, o1b);
  k_gemm<1><<<dim3(8, 128), 256, 0, stream>>>(o1b, WfcT, (void*)o2);
  k_ln<false><<<dim3(16384), 256, 0, stream>>>(o2, o1f, lng, lnb, out, nullptr);
}

// Round 3
// 977.233 us; speedup vs baseline: 2.5660x; 2.5660x over previous
//
#include <hip/hip_runtime.h>
#include <hip/hip_bf16.h>
#include <stdint.h>

typedef __attribute__((ext_vector_type(4))) float f32x4;
typedef __attribute__((ext_vector_type(8))) short bf16x8;
typedef __attribute__((ext_vector_type(4))) unsigned short us4;
typedef __attribute__((ext_vector_type(8))) unsigned short us8;

static constexpr int Bb = 8, Ss = 2048, Dd = 1024, Hh = 16, DHh = 64;
static constexpr int Mm = Bb * Ss;   // 16384
#define DEVI static __device__ __forceinline__

DEVI float bf2f(unsigned short u) {
  union { unsigned int i; float f; } v; v.i = ((unsigned int)u) << 16; return v.f;
}
DEVI unsigned short f2bf(float f) {
  union { float f; unsigned int i; } v; v.f = f;
  unsigned int r = v.i + 0x7FFFu + ((v.i >> 16) & 1u);
  return (unsigned short)(r >> 16);
}

// ---- W [K=1024][N=1024] f32 -> WT bf16 [N][K] ----
__global__ __launch_bounds__(256) void k_transpose_w(const float* __restrict__ W,
                                                     unsigned short* __restrict__ WT) {
  __shared__ float tile[32][33];
  const int n0 = blockIdx.x * 32, k0 = blockIdx.y * 32;
  const int t = threadIdx.x, tr = t >> 5, tc = t & 31;
#pragma unroll
  for (int i = 0; i < 4; i++) {
    int r = tr + 8 * i;
    tile[r][tc] = W[(size_t)(k0 + r) * 1024 + n0 + tc];
  }
  __syncthreads();
#pragma unroll
  for (int i = 0; i < 4; i++) {
    int r = tr + 8 * i;
    WT[(size_t)(n0 + r) * 1024 + k0 + tc] = f2bf(tile[tc][r]);
  }
}

// ---- f32 -> bf16 elementwise ----
__global__ __launch_bounds__(256) void k_cvt(const float* __restrict__ x,
                                             unsigned short* __restrict__ y) {
  const int n4 = (Mm * Dd) / 4;
  for (int i = blockIdx.x * 256 + threadIdx.x; i < n4; i += gridDim.x * 256) {
    f32x4 v = ((const f32x4*)x)[i];
    us4 o = { f2bf(v.x), f2bf(v.y), f2bf(v.z), f2bf(v.w) };
    ((us4*)y)[i] = o;
  }
}

// ---- A[f][d] f32 -> At[d][f] bf16 (64x64) ----
__global__ __launch_bounds__(256) void k_prep_at(const float* __restrict__ A,
                                                 unsigned short* __restrict__ At) {
  int t = blockIdx.x * 256 + threadIdx.x;   // 0..4095
  int d = t >> 6, f = t & 63;
  At[d * 64 + f] = f2bf(A[f * 64 + d]);
}

// ---- Qmid/Kmid = in[16384,1024] @ W1[1024,32] (f32) ----
__global__ __launch_bounds__(256) void k_qkmid(const float* __restrict__ inQ, const float* __restrict__ inK,
                                               const float* __restrict__ Wq1, const float* __restrict__ Wk1,
                                               float* __restrict__ Qmid, float* __restrict__ Kmid) {
  const float* in = blockIdx.y ? inK : inQ;
  const float* W  = blockIdx.y ? Wk1 : Wq1;
  float* outp     = blockIdx.y ? Kmid : Qmid;
  __shared__ float rows[8][1024];
  const int r0 = blockIdx.x * 8;
  const int t = threadIdx.x;
  const f32x4* src = (const f32x4*)(in + (size_t)r0 * 1024);
  f32x4* dstl = (f32x4*)rows;
#pragma unroll
  for (int i = 0; i < 8; i++) dstl[t + 256 * i] = src[t + 256 * i];
  __syncthreads();
  const int g = t >> 5, j = t & 31;
  float acc = 0.f;
#pragma unroll 8
  for (int k = 0; k < 1024; k++) acc += rows[g][k] * W[k * 32 + j];
  outp[(size_t)(r0 + g) * 32 + j] = acc;
}

// ---- Q/K = mid[16384,32] @ W2[32,1024] -> bf16 [b,h,s,f] ----
__global__ __launch_bounds__(256) void k_qkexpand(const float* __restrict__ Qmid, const float* __restrict__ Kmid,
                                                  const float* __restrict__ Wq2, const float* __restrict__ Wk2,
                                                  unsigned short* __restrict__ Qp, unsigned short* __restrict__ Kp) {
  const float* mid = blockIdx.y ? Kmid : Qmid;
  const float* W   = blockIdx.y ? Wk2 : Wq2;
  unsigned short* outp = blockIdx.y ? Kp : Qp;
  __shared__ float sv[16][32];
  const int r0 = blockIdx.x * 16;
  const int t = threadIdx.x;
  ((float*)sv)[t]       = mid[(size_t)r0 * 32 + t];
  ((float*)sv)[t + 256] = mid[(size_t)r0 * 32 + t + 256];
  __syncthreads();
  const int c0 = t * 4;
  f32x4 acc[16];
#pragma unroll
  for (int ri = 0; ri < 16; ri++) acc[ri] = (f32x4){0.f, 0.f, 0.f, 0.f};
#pragma unroll
  for (int k = 0; k < 32; k++) {
    f32x4 w = *(const f32x4*)&W[k * 1024 + c0];
#pragma unroll
    for (int ri = 0; ri < 16; ri++) acc[ri] += sv[ri][k] * w;
  }
  const int h = c0 >> 6, f = c0 & 63;
#pragma unroll
  for (int ri = 0; ri < 16; ri++) {
    int r = r0 + ri;
    int b = r >> 11, s = r & 2047;
    us4 o = { f2bf(acc[ri].x), f2bf(acc[ri].y), f2bf(acc[ri].z), f2bf(acc[ri].w) };
    *(us4*)&outp[(((size_t)(b * 16 + h) * 2048) + s) * 64 + f] = o;
  }
}

// ---- per-(b,h) transpose: [2048][64] bf16 -> [64][2048] bf16 ----
__global__ __launch_bounds__(256) void k_transpose_bh(const unsigned short* __restrict__ src,
                                                      unsigned short* __restrict__ dst) {
  __shared__ unsigned short tile[64][72];
  const int bh = blockIdx.y, s0 = blockIdx.x * 64;
  const int t = threadIdx.x;
  {
    int sl = t >> 2, fc = (t & 3) * 16;
    const unsigned short* sp = src + ((size_t)bh * 2048 + s0 + sl) * 64 + fc;
    *(us8*)&tile[sl][fc]     = *(const us8*)sp;
    *(us8*)&tile[sl][fc + 8] = *(const us8*)(sp + 8);
  }
  __syncthreads();
  {
    int f = t >> 2, sc = (t & 3) * 16;
    unsigned short* dp = dst + ((size_t)bh * 64 + f) * 2048 + s0 + sc;
    us8 a, bq;
#pragma unroll
    for (int i = 0; i < 8; i++) a[i] = tile[sc + i][f];
#pragma unroll
    for (int i = 0; i < 8; i++) bq[i] = tile[sc + 8 + i][f];
    *(us8*)dp = a;
    *(us8*)(dp + 8) = bq;
  }
}

// ---- bf16 MFMA GEMM: A[M,1024] bf16 @ (BT[N,1024])^T, 128x128 tile, BK=64 ----
template <int EPI>
__global__ __launch_bounds__(256) void k_gemm(const unsigned short* __restrict__ Ag,
                                              const unsigned short* __restrict__ BTg,
                                              void* __restrict__ Cout) {
  __shared__ unsigned short As[128 * 64];
  __shared__ unsigned short Bs[128 * 64];
  const int m0 = blockIdx.y * 128, n0 = blockIdx.x * 128;
  const int t = threadIdx.x;
  const int w = t >> 6, l = t & 63;
  const int wr = w >> 1, wc = w & 1;
  const int g4 = l >> 4, l16 = l & 15;
  f32x4 acc[4][4];
#pragma unroll
  for (int i = 0; i < 4; i++)
#pragma unroll
    for (int jj = 0; jj < 4; jj++) acc[i][jj] = (f32x4){0.f, 0.f, 0.f, 0.f};

  const int srow = t >> 1, shalf = (t & 1) * 32;
  const us8* ga = (const us8*)(Ag  + (size_t)(m0 + srow) * 1024 + shalf);
  const us8* gb = (const us8*)(BTg + (size_t)(n0 + srow) * 1024 + shalf);
  const int swz = (srow & 7) << 4;
#pragma unroll 1
  for (int kt = 0; kt < 16; kt++) {
    __syncthreads();
#pragma unroll
    for (int c = 0; c < 4; c++) {
      int kb = (shalf + c * 8) * 2;
      *(us8*)&As[srow * 64 + ((kb ^ swz) >> 1)] = ga[c];
      *(us8*)&Bs[srow * 64 + ((kb ^ swz) >> 1)] = gb[c];
    }
    ga += 8; gb += 8;
    __syncthreads();
#pragma unroll
    for (int kk = 0; kk < 64; kk += 32) {
      bf16x8 af[4], bfr[4];
      const int kbyte = (kk + 8 * g4) * 2;
#pragma unroll
      for (int mt = 0; mt < 4; mt++) {
        int row = wr * 64 + mt * 16 + l16;
        af[mt] = *(const bf16x8*)&As[row * 64 + ((kbyte ^ ((row & 7) << 4)) >> 1)];
      }
#pragma unroll
      for (int nt = 0; nt < 4; nt++) {
        int row = wc * 64 + nt * 16 + l16;
        bfr[nt] = *(const bf16x8*)&Bs[row * 64 + ((kbyte ^ ((row & 7) << 4)) >> 1)];
      }
#pragma unroll
      for (int mt = 0; mt < 4; mt++)
#pragma unroll
        for (int nt = 0; nt < 4; nt++)
          acc[mt][nt] = __builtin_amdgcn_mfma_f32_16x16x32_bf16(af[mt], bfr[nt], acc[mt][nt], 0, 0, 0);
    }
  }
#pragma unroll
  for (int mt = 0; mt < 4; mt++)
#pragma unroll
    for (int nt = 0; nt < 4; nt++)
#pragma unroll
      for (int r = 0; r < 4; r++) {
        int m = m0 + wr * 64 + mt * 16 + g4 * 4 + r;
        int n = n0 + wc * 64 + nt * 16 + l16;
        float v = acc[mt][nt][r];
        if (EPI == 0) {
          int b = m >> 11, s = m & 2047, h = n >> 6, f = n & 63;
          ((unsigned short*)Cout)[(((size_t)(b * 16 + h) * 2048) + s) * 64 + f] = f2bf(v);
        } else {
          ((float*)Cout)[(size_t)m * 1024 + n] = v;
        }
      }
}

// ---- stage 1 (MFMA): per block = one (b,h). S = K@At^T via mfma, online softmax over s,
// pass B: attn = e*invl -> global, P(bf16)->LDS, VV += P@V via mfma. No per-lane arrays.
__global__ __launch_bounds__(512) void k_stage1m(const unsigned short* __restrict__ Kp,
                                                 const unsigned short* __restrict__ VpT,
                                                 const unsigned short* __restrict__ At,
                                                 float* __restrict__ attn_out,
                                                 float* __restrict__ VVn) {
  __shared__ unsigned short Ks[256 * 64];   // [s][f] swz
  __shared__ unsigned short VTs[64 * 256];  // [f][s] swz
  __shared__ unsigned short Ps[64 * 256];   // [d][s] swz
  __shared__ float mred[512], lred[512], mfin[64], linv[64];
  const int bh = blockIdx.x;
  const int t = threadIdx.x;               // 0..511
  const int w = t >> 6, l = t & 63;
  const int l16 = l & 15, g4 = l >> 4;
  const unsigned short* kg = Kp  + (size_t)bh * 131072;
  const unsigned short* vg = VpT + (size_t)bh * 131072;

  // hoisted B-frags of A^T: B[k=f][n=d] = At[d][f]
  bf16x8 bfr[4][2];
#pragma unroll
  for (int nt = 0; nt < 4; nt++)
#pragma unroll
    for (int ks = 0; ks < 2; ks++)
      bfr[nt][ks] = *(const bf16x8*)&At[(nt * 16 + l16) * 64 + ks * 32 + g4 * 8];

  float m4[4], l4[4];
#pragma unroll
  for (int nt = 0; nt < 4; nt++) { m4[nt] = -1e30f; l4[nt] = 0.f; }

  // ---------------- pass A: online (m,l) per column d ----------------
  for (int st = 0; st < 8; st++) {
    __syncthreads();
#pragma unroll
    for (int i = 0; i < 4; i++) {
      int chunk = t + 512 * i;
      int row = chunk >> 3, fo = (chunk & 7) * 8;
      us8 v = *(const us8*)&kg[(size_t)(st * 256 + row) * 64 + fo];
      *(us8*)&Ks[row * 64 + (((fo * 2) ^ ((row & 7) << 4)) >> 1)] = v;
    }
    __syncthreads();
    f32x4 s_[2][4];
#pragma unroll
    for (int mt = 0; mt < 2; mt++)
#pragma unroll
      for (int nt = 0; nt < 4; nt++) s_[mt][nt] = (f32x4){0.f, 0.f, 0.f, 0.f};
#pragma unroll
    for (int mt = 0; mt < 2; mt++) {
      int ar = w * 32 + mt * 16 + l16;
#pragma unroll
      for (int ks = 0; ks < 2; ks++) {
        bf16x8 af = *(const bf16x8*)&Ks[ar * 64 + (((ks * 64 + g4 * 16) ^ ((ar & 7) << 4)) >> 1)];
#pragma unroll
        for (int nt = 0; nt < 4; nt++)
          s_[mt][nt] = __builtin_amdgcn_mfma_f32_16x16x32_bf16(af, bfr[nt][ks], s_[mt][nt], 0, 0, 0);
      }
    }
#pragma unroll
    for (int nt = 0; nt < 4; nt++) {
      float tm = s_[0][nt][0];
#pragma unroll
      for (int r = 1; r < 4; r++) tm = fmaxf(tm, s_[0][nt][r]);
#pragma unroll
      for (int r = 0; r < 4; r++) tm = fmaxf(tm, s_[1][nt][r]);
      tm *= 0.125f;
      float mn = fmaxf(m4[nt], tm);
      float sum = 0.f;
#pragma unroll
      for (int mt = 0; mt < 2; mt++)
#pragma unroll
        for (int r = 0; r < 4; r++) sum += __expf(s_[mt][nt][r] * 0.125f - mn);
      l4[nt] = l4[nt] * __expf(m4[nt] - mn) + sum;
      m4[nt] = mn;
    }
  }
  // reduce across the 4 row-groups (lanes sharing l16)
#pragma unroll
  for (int nt = 0; nt < 4; nt++) {
#pragma unroll
    for (int off = 16; off < 64; off <<= 1) {
      float m2 = __shfl_xor(m4[nt], off);
      float l2 = __shfl_xor(l4[nt], off);
      float mn = fmaxf(m4[nt], m2);
      l4[nt] = l4[nt] * __expf(m4[nt] - mn) + l2 * __expf(m2 - mn);
      m4[nt] = mn;
    }
  }
  if (l < 16) {
#pragma unroll
    for (int nt = 0; nt < 4; nt++) {
      mred[w * 64 + nt * 16 + l] = m4[nt];
      lred[w * 64 + nt * 16 + l] = l4[nt];
    }
  }
  __syncthreads();
  if (w == 0) {
    float m = -1e30f;
#pragma unroll
    for (int wv = 0; wv < 8; wv++) m = fmaxf(m, mred[wv * 64 + l]);
    float ls = 0.f;
#pragma unroll
    for (int wv = 0; wv < 8; wv++) ls += lred[wv * 64 + l] * __expf(mred[wv * 64 + l] - m);
    mfin[l] = m;
    linv[l] = 1.f / ls;
  }

  // ---------------- pass B: attn out + VV accumulate ----------------
  f32x4 vv[2];
  vv[0] = (f32x4){0.f, 0.f, 0.f, 0.f};
  vv[1] = (f32x4){0.f, 0.f, 0.f, 0.f};
  const int mtv = w & 3, nbase = (w >> 2) * 2;
  float* aout = attn_out + (size_t)bh * 131072;
  for (int st = 0; st < 8; st++) {
    __syncthreads();
#pragma unroll
    for (int i = 0; i < 4; i++) {
      int chunk = t + 512 * i;
      {
        int row = chunk >> 3, fo = (chunk & 7) * 8;
        us8 v = *(const us8*)&kg[(size_t)(st * 256 + row) * 64 + fo];
        *(us8*)&Ks[row * 64 + (((fo * 2) ^ ((row & 7) << 4)) >> 1)] = v;
      }
      {
        int fr = chunk >> 5, so = (chunk & 31) * 8;
        us8 v = *(const us8*)&vg[(size_t)fr * 2048 + st * 256 + so];
        *(us8*)&VTs[fr * 256 + (((so * 2) ^ ((fr & 7) << 4)) >> 1)] = v;
      }
    }
    __syncthreads();
    f32x4 s_[2][4];
#pragma unroll
    for (int mt = 0; mt < 2; mt++)
#pragma unroll
      for (int nt = 0; nt < 4; nt++) s_[mt][nt] = (f32x4){0.f, 0.f, 0.f, 0.f};
#pragma unroll
    for (int mt = 0; mt < 2; mt++) {
      int ar = w * 32 + mt * 16 + l16;
#pragma unroll
      for (int ks = 0; ks < 2; ks++) {
        bf16x8 af = *(const bf16x8*)&Ks[ar * 64 + (((ks * 64 + g4 * 16) ^ ((ar & 7) << 4)) >> 1)];
#pragma unroll
        for (int nt = 0; nt < 4; nt++)
          s_[mt][nt] = __builtin_amdgcn_mfma_f32_16x16x32_bf16(af, bfr[nt][ks], s_[mt][nt], 0, 0, 0);
      }
    }
#pragma unroll
    for (int mt = 0; mt < 2; mt++) {
      int sg = w * 32 + mt * 16 + g4 * 4;
#pragma unroll
      for (int nt = 0; nt < 4; nt++) {
        int d = nt * 16 + l16;
        float mf = mfin[d], il = linv[d];
        f32x4 ev;
#pragma unroll
        for (int r = 0; r < 4; r++) ev[r] = __expf(s_[mt][nt][r] * 0.125f - mf);
        f32x4 av = ev * il;
        *(f32x4*)&aout[(size_t)d * 2048 + st * 256 + sg] = av;
        us4 pb = { f2bf(ev.x), f2bf(ev.y), f2bf(ev.z), f2bf(ev.w) };
        *(us4*)&Ps[d * 256 + (((sg * 2) ^ ((d & 7) << 4)) >> 1)] = pb;
      }
    }
    __syncthreads();
#pragma unroll
    for (int ks = 0; ks < 8; ks++) {
      int ar = mtv * 16 + l16;
      bf16x8 pa = *(const bf16x8*)&Ps[ar * 256 + (((ks * 64 + g4 * 16) ^ ((ar & 7) << 4)) >> 1)];
#pragma unroll
      for (int j = 0; j < 2; j++) {
        int fr = (nbase + j) * 16 + l16;
        bf16x8 vb = *(const bf16x8*)&VTs[fr * 256 + (((ks * 64 + g4 * 16) ^ ((fr & 7) << 4)) >> 1)];
        vv[j] = __builtin_amdgcn_mfma_f32_16x16x32_bf16(pa, vb, vv[j], 0, 0, 0);
      }
    }
  }
#pragma unroll
  for (int j = 0; j < 2; j++)
#pragma unroll
    for (int r = 0; r < 4; r++) {
      int d = mtv * 16 + g4 * 4 + r;
      int f = (nbase + j) * 16 + l16;
      VVn[(size_t)bh * 4096 + d * 64 + f] = vv[j][r] * linv[d];
    }
}

// ---- stage 2: scores2 = 0.125*Q A^T, softmax over d (64), VVV = attn2@VV, scatter reshape into X
__global__ __launch_bounds__(256) void k_stage2(const unsigned short* __restrict__ Qp,
                                                const float* __restrict__ Aw,
                                                const float* __restrict__ VVn, float* __restrict__ X) {
  __shared__ float A2[64][65];
  __shared__ float VVl[64][65];
  __shared__ float Qt[64][64];
  __shared__ float At[4][64];
  const int bh = blockIdx.y, b = bh >> 4, h = bh & 15;
  const int s0 = blockIdx.x * 64;
  const int t = threadIdx.x;
  const int wv = t >> 6, l = t & 63;
  for (int i = t; i < 4096; i += 256) {
    int dd = i >> 6, ff = i & 63;
    A2[dd][ff]  = Aw[i];
    VVl[dd][ff] = VVn[(size_t)bh * 4096 + i];
  }
  {
    int sl = t >> 2, fc = (t & 3) * 16;
    const unsigned short* qp = Qp + ((size_t)bh * 2048 + s0 + sl) * 64 + fc;
#pragma unroll
    for (int u = 0; u < 4; u++) {
      us4 q = *(const us4*)(qp + u * 4);
      f32x4 qf = { bf2f(q.x), bf2f(q.y), bf2f(q.z), bf2f(q.w) };
      *(f32x4*)&Qt[sl][fc + u * 4] = qf;
    }
  }
  __syncthreads();
  for (int i = 0; i < 16; i++) {
    const int sl = i * 4 + wv;
    float sc = 0.f;
#pragma unroll 16
    for (int f = 0; f < 64; f++) sc += Qt[sl][f] * A2[l][f];
    sc *= 0.125f;
    float mx = sc;
#pragma unroll
    for (int o = 1; o < 64; o <<= 1) mx = fmaxf(mx, __shfl_xor(mx, o));
    float e = __expf(sc - mx);
    float sm = e;
#pragma unroll
    for (int o = 1; o < 64; o <<= 1) sm += __shfl_xor(sm, o);
    At[wv][l] = e / sm;
    __syncthreads();
    {
      float v = 0.f;
#pragma unroll 16
      for (int dd = 0; dd < 64; dd++) v += At[wv][dd] * VVl[dd][l];
      const int ss = s0 + sl;
      const int jj = h * 128 + (ss >> 4);
      const int cc = (ss & 15) * 64 + l;
      X[((size_t)(b * 2048 + jj)) * 1024 + cc] = v;
    }
    __syncthreads();
  }
}

// ---- residual + LayerNorm; optionally also write bf16 copy ----
template <bool WB>
__global__ __launch_bounds__(256) void k_ln(const float* __restrict__ xa, const float* __restrict__ xb,
                                            const float* __restrict__ g, const float* __restrict__ bbv,
                                            float* __restrict__ outf, unsigned short* __restrict__ outb) {
  __shared__ float red[2][4];
  const size_t row = blockIdx.x;
  const int t = threadIdx.x;
  const int wv = t >> 6, l = t & 63;
  f32x4 va = ((const f32x4*)(xa + row * 1024))[t];
  f32x4 vb = ((const f32x4*)(xb + row * 1024))[t];
  f32x4 v = va + vb;
  float s = v.x + v.y + v.z + v.w;
  float q = v.x * v.x + v.y * v.y + v.z * v.z + v.w * v.w;
#pragma unroll
  for (int o = 1; o < 64; o <<= 1) { s += __shfl_xor(s, o); q += __shfl_xor(q, o); }
  if (l == 0) { red[0][wv] = s; red[1][wv] = q; }
  __syncthreads();
  s = red[0][0] + red[0][1] + red[0][2] + red[0][3];
  q = red[1][0] + red[1][1] + red[1][2] + red[1][3];
  const float mean = s * (1.f / 1024.f);
  const float var = q * (1.f / 1024.f) - mean * mean;
  const float rstd = rsqrtf(var + 1e-5f);
  f32x4 gg = ((const f32x4*)g)[t];
  f32x4 bv = ((const f32x4*)bbv)[t];
  f32x4 o;
  o.x = (v.x - mean) * rstd * gg.x + bv.x;
  o.y = (v.y - mean) * rstd * gg.y + bv.y;
  o.z = (v.z - mean) * rstd * gg.z + bv.z;
  o.w = (v.w - mean) * rstd * gg.w + bv.w;
  ((f32x4*)(outf + row * 1024))[t] = o;
  if (WB) {
    us4 ob = { f2bf(o.x), f2bf(o.y), f2bf(o.z), f2bf(o.w) };
    ((us4*)(outb + row * 1024))[t] = ob;
  }
}

extern "C" void kernel_launch(void* const* d_in, const int* in_sizes, int n_in,
                              void* d_out, int out_size, void* d_ws, size_t ws_size,
                              hipStream_t stream) {
  const float* inQ = (const float*)d_in[0];
  const float* inK = (const float*)d_in[1];
  const float* inV = (const float*)d_in[2];
  const float* Wq1 = (const float*)d_in[3];
  const float* Wq2 = (const float*)d_in[4];
  const float* Wk1 = (const float*)d_in[5];
  const float* Wk2 = (const float*)d_in[6];
  const float* Wv  = (const float*)d_in[7];
  const float* Wfc = (const float*)d_in[8];
  const float* Aw  = (const float*)d_in[9];
  const float* lng = (const float*)d_in[10];
  const float* lnb = (const float*)d_in[11];
  float* out = (float*)d_out;
  float* attn_out = out + (size_t)Mm * Dd;   // output 1: attn_VV [8,16,64,2048]

  char* ws = (char*)d_ws;
  unsigned short* WvT  = (unsigned short*)(ws + 0ull);           //  2 MB
  unsigned short* WfcT = (unsigned short*)(ws + 2097152ull);     //  2 MB
  float* Qmid          = (float*)(ws + 4194304ull);              //  2 MB (-> At bf16 after qkexpand)
  float* Kmid          = (float*)(ws + 6291456ull);              //  2 MB
  unsigned short* Qp   = (unsigned short*)(ws + 8388608ull);     // 32 MB
  unsigned short* Kp   = (unsigned short*)(ws + 41943040ull);    // 32 MB -> later o1 bf16
  unsigned short* KpT  = (unsigned short*)(ws + 75497472ull);    // (unused now) -> o2 (64 MB f32)
  unsigned short* VpT  = (unsigned short*)(ws + 109051904ull);   // 32 MB
  unsigned short* Vbf  = (unsigned short*)(ws + 142606336ull);   // 32 MB -> later X / o1f (64 MB f32)
  unsigned short* Vp   = (unsigned short*)(ws + 176160768ull);   // 32 MB
  float* VVn           = (float*)(ws + 209715200ull);            //  2 MB
  unsigned short* Atb = (unsigned short*)(ws + 4194304ull);      // 8 KB, reuses Qmid region
  float* o2  = (float*)(ws + 75497472ull);
  float* X   = (float*)(ws + 142606336ull);
  float* o1f = X;
  unsigned short* o1b = Kp;
  (void)KpT;

  k_transpose_w<<<dim3(32, 32), 256, 0, stream>>>(Wv, WvT);
  k_transpose_w<<<dim3(32, 32), 256, 0, stream>>>(Wfc, WfcT);
  k_cvt<<<dim3(4096), 256, 0, stream>>>(inV, Vbf);
  k_qkmid<<<dim3(2048, 2), 256, 0, stream>>>(inQ, inK, Wq1, Wk1, Qmid, Kmid);
  k_qkexpand<<<dim3(1024, 2), 256, 0, stream>>>(Qmid, Kmid, Wq2, Wk2, Qp, Kp);
  k_prep_at<<<dim3(16), 256, 0, stream>>>(Aw, Atb);
  k_gemm<0><<<dim3(8, 128), 256, 0, stream>>>(Vbf, WvT, (void*)Vp);
  k_transpose_bh<<<dim3(32, 128), 256, 0, stream>>>(Vp, VpT);
  k_stage1m<<<dim3(128), 512, 0, stream>>>(Kp, VpT, Atb, attn_out, VVn);
  k_stage2<<<dim3(32, 128), 256, 0, stream>>>(Qp, Aw, VVn, X);
  k_ln<true><<<dim3(16384), 256, 0, stream>>>(X, inQ, lng, lnb, o1f, o1b);
  k_gemm<1><<<dim3(8, 128), 256, 0, stream>>>(o1b, WfcT, (void*)o2);
  k_ln<false><<<dim3(16384), 256, 0, stream>>>(o2, o1f, lng, lnb, out, nullptr);
}

// Round 4
// 781.867 us; speedup vs baseline: 3.2071x; 1.2499x over previous
//
#include <hip/hip_runtime.h>
#include <hip/hip_bf16.h>
#include <stdint.h>

typedef __attribute__((ext_vector_type(4))) float f32x4;
typedef __attribute__((ext_vector_type(8))) short bf16x8;
typedef __attribute__((ext_vector_type(4))) unsigned short us4;
typedef __attribute__((ext_vector_type(8))) unsigned short us8;

static constexpr int Bb = 8, Ss = 2048, Dd = 1024, Hh = 16, DHh = 64;
static constexpr int Mm = Bb * Ss;   // 16384
#define DEVI static __device__ __forceinline__

DEVI float bf2f(unsigned short u) {
  union { unsigned int i; float f; } v; v.i = ((unsigned int)u) << 16; return v.f;
}
DEVI unsigned short f2bf(float f) {
  union { float f; unsigned int i; } v; v.f = f;
  unsigned int r = v.i + 0x7FFFu + ((v.i >> 16) & 1u);
  return (unsigned short)(r >> 16);
}

// ---- W [K=1024][N=1024] f32 -> WT bf16 [N][K] ----
__global__ __launch_bounds__(256) void k_transpose_w(const float* __restrict__ W,
                                                     unsigned short* __restrict__ WT) {
  __shared__ float tile[32][33];
  const int n0 = blockIdx.x * 32, k0 = blockIdx.y * 32;
  const int t = threadIdx.x, tr = t >> 5, tc = t & 31;
#pragma unroll
  for (int i = 0; i < 4; i++) {
    int r = tr + 8 * i;
    tile[r][tc] = W[(size_t)(k0 + r) * 1024 + n0 + tc];
  }
  __syncthreads();
#pragma unroll
  for (int i = 0; i < 4; i++) {
    int r = tr + 8 * i;
    WT[(size_t)(n0 + r) * 1024 + k0 + tc] = f2bf(tile[tc][r]);
  }
}

// ---- f32 -> bf16 elementwise ----
__global__ __launch_bounds__(256) void k_cvt(const float* __restrict__ x,
                                             unsigned short* __restrict__ y) {
  const int n4 = (Mm * Dd) / 4;
  for (int i = blockIdx.x * 256 + threadIdx.x; i < n4; i += gridDim.x * 256) {
    f32x4 v = ((const f32x4*)x)[i];
    us4 o = { f2bf(v.x), f2bf(v.y), f2bf(v.z), f2bf(v.w) };
    ((us4*)y)[i] = o;
  }
}

// ---- A[f][d] f32 -> At[d][f] bf16 (transposed, stage1) + Ab bf16 straight (stage2) ----
__global__ __launch_bounds__(256) void k_prep_at(const float* __restrict__ A,
                                                 unsigned short* __restrict__ At,
                                                 unsigned short* __restrict__ Ab) {
  int t = blockIdx.x * 256 + threadIdx.x;   // 0..4095
  int d = t >> 6, f = t & 63;
  At[d * 64 + f] = f2bf(A[f * 64 + d]);
  Ab[t] = f2bf(A[t]);
}

// ---- Qmid/Kmid = in[16384,1024] @ W1[1024,32] (f32) ----
__global__ __launch_bounds__(256) void k_qkmid(const float* __restrict__ inQ, const float* __restrict__ inK,
                                               const float* __restrict__ Wq1, const float* __restrict__ Wk1,
                                               float* __restrict__ Qmid, float* __restrict__ Kmid) {
  const float* in = blockIdx.y ? inK : inQ;
  const float* W  = blockIdx.y ? Wk1 : Wq1;
  float* outp     = blockIdx.y ? Kmid : Qmid;
  __shared__ float rows[8][1024];
  const int r0 = blockIdx.x * 8;
  const int t = threadIdx.x;
  const f32x4* src = (const f32x4*)(in + (size_t)r0 * 1024);
  f32x4* dstl = (f32x4*)rows;
#pragma unroll
  for (int i = 0; i < 8; i++) dstl[t + 256 * i] = src[t + 256 * i];
  __syncthreads();
  const int g = t >> 5, j = t & 31;
  float acc = 0.f;
#pragma unroll 8
  for (int k = 0; k < 1024; k++) acc += rows[g][k] * W[k * 32 + j];
  outp[(size_t)(r0 + g) * 32 + j] = acc;
}

// ---- Q/K = mid[16384,32] @ W2[32,1024] -> bf16 [b,h,s,f] ----
__global__ __launch_bounds__(256) void k_qkexpand(const float* __restrict__ Qmid, const float* __restrict__ Kmid,
                                                  const float* __restrict__ Wq2, const float* __restrict__ Wk2,
                                                  unsigned short* __restrict__ Qp, unsigned short* __restrict__ Kp) {
  const float* mid = blockIdx.y ? Kmid : Qmid;
  const float* W   = blockIdx.y ? Wk2 : Wq2;
  unsigned short* outp = blockIdx.y ? Kp : Qp;
  __shared__ float sv[16][32];
  const int r0 = blockIdx.x * 16;
  const int t = threadIdx.x;
  ((float*)sv)[t]       = mid[(size_t)r0 * 32 + t];
  ((float*)sv)[t + 256] = mid[(size_t)r0 * 32 + t + 256];
  __syncthreads();
  const int c0 = t * 4;
  f32x4 acc[16];
#pragma unroll
  for (int ri = 0; ri < 16; ri++) acc[ri] = (f32x4){0.f, 0.f, 0.f, 0.f};
#pragma unroll
  for (int k = 0; k < 32; k++) {
    f32x4 w = *(const f32x4*)&W[k * 1024 + c0];
#pragma unroll
    for (int ri = 0; ri < 16; ri++) acc[ri] += sv[ri][k] * w;
  }
  const int h = c0 >> 6, f = c0 & 63;
#pragma unroll
  for (int ri = 0; ri < 16; ri++) {
    int r = r0 + ri;
    int b = r >> 11, s = r & 2047;
    us4 o = { f2bf(acc[ri].x), f2bf(acc[ri].y), f2bf(acc[ri].z), f2bf(acc[ri].w) };
    *(us4*)&outp[(((size_t)(b * 16 + h) * 2048) + s) * 64 + f] = o;
  }
}

// ---- per-(b,h) transpose: [2048][64] bf16 -> [64][2048] bf16 ----
__global__ __launch_bounds__(256) void k_transpose_bh(const unsigned short* __restrict__ src,
                                                      unsigned short* __restrict__ dst) {
  __shared__ unsigned short tile[64][72];
  const int bh = blockIdx.y, s0 = blockIdx.x * 64;
  const int t = threadIdx.x;
  {
    int sl = t >> 2, fc = (t & 3) * 16;
    const unsigned short* sp = src + ((size_t)bh * 2048 + s0 + sl) * 64 + fc;
    *(us8*)&tile[sl][fc]     = *(const us8*)sp;
    *(us8*)&tile[sl][fc + 8] = *(const us8*)(sp + 8);
  }
  __syncthreads();
  {
    int f = t >> 2, sc = (t & 3) * 16;
    unsigned short* dp = dst + ((size_t)bh * 64 + f) * 2048 + s0 + sc;
    us8 a, bq;
#pragma unroll
    for (int i = 0; i < 8; i++) a[i] = tile[sc + i][f];
#pragma unroll
    for (int i = 0; i < 8; i++) bq[i] = tile[sc + 8 + i][f];
    *(us8*)dp = a;
    *(us8*)(dp + 8) = bq;
  }
}

// ---- bf16 MFMA GEMM: A[M,1024] bf16 @ (BT[N,1024])^T, 128x128 tile, BK=64 ----
template <int EPI>
__global__ __launch_bounds__(256) void k_gemm(const unsigned short* __restrict__ Ag,
                                              const unsigned short* __restrict__ BTg,
                                              void* __restrict__ Cout) {
  __shared__ unsigned short As[128 * 64];
  __shared__ unsigned short Bs[128 * 64];
  const int m0 = blockIdx.y * 128, n0 = blockIdx.x * 128;
  const int t = threadIdx.x;
  const int w = t >> 6, l = t & 63;
  const int wr = w >> 1, wc = w & 1;
  const int g4 = l >> 4, l16 = l & 15;
  f32x4 acc[4][4];
#pragma unroll
  for (int i = 0; i < 4; i++)
#pragma unroll
    for (int jj = 0; jj < 4; jj++) acc[i][jj] = (f32x4){0.f, 0.f, 0.f, 0.f};

  const int srow = t >> 1, shalf = (t & 1) * 32;
  const us8* ga = (const us8*)(Ag  + (size_t)(m0 + srow) * 1024 + shalf);
  const us8* gb = (const us8*)(BTg + (size_t)(n0 + srow) * 1024 + shalf);
  const int swz = (srow & 7) << 4;
#pragma unroll 1
  for (int kt = 0; kt < 16; kt++) {
    __syncthreads();
#pragma unroll
    for (int c = 0; c < 4; c++) {
      int kb = (shalf + c * 8) * 2;
      *(us8*)&As[srow * 64 + ((kb ^ swz) >> 1)] = ga[c];
      *(us8*)&Bs[srow * 64 + ((kb ^ swz) >> 1)] = gb[c];
    }
    ga += 8; gb += 8;
    __syncthreads();
#pragma unroll
    for (int kk = 0; kk < 64; kk += 32) {
      bf16x8 af[4], bfr[4];
      const int kbyte = (kk + 8 * g4) * 2;
#pragma unroll
      for (int mt = 0; mt < 4; mt++) {
        int row = wr * 64 + mt * 16 + l16;
        af[mt] = *(const bf16x8*)&As[row * 64 + ((kbyte ^ ((row & 7) << 4)) >> 1)];
      }
#pragma unroll
      for (int nt = 0; nt < 4; nt++) {
        int row = wc * 64 + nt * 16 + l16;
        bfr[nt] = *(const bf16x8*)&Bs[row * 64 + ((kbyte ^ ((row & 7) << 4)) >> 1)];
      }
#pragma unroll
      for (int mt = 0; mt < 4; mt++)
#pragma unroll
        for (int nt = 0; nt < 4; nt++)
          acc[mt][nt] = __builtin_amdgcn_mfma_f32_16x16x32_bf16(af[mt], bfr[nt], acc[mt][nt], 0, 0, 0);
    }
  }
#pragma unroll
  for (int mt = 0; mt < 4; mt++)
#pragma unroll
    for (int nt = 0; nt < 4; nt++)
#pragma unroll
      for (int r = 0; r < 4; r++) {
        int m = m0 + wr * 64 + mt * 16 + g4 * 4 + r;
        int n = n0 + wc * 64 + nt * 16 + l16;
        float v = acc[mt][nt][r];
        if (EPI == 0) {
          int b = m >> 11, s = m & 2047, h = n >> 6, f = n & 63;
          ((unsigned short*)Cout)[(((size_t)(b * 16 + h) * 2048) + s) * 64 + f] = f2bf(v);
        } else {
          ((float*)Cout)[(size_t)m * 1024 + n] = v;
        }
      }
}

// ---- stage 1 (MFMA): per block = one (b,h). S = K@At^T via mfma, online softmax over s,
// pass B: attn = e*invl -> global, P(bf16)->LDS, VV += P@V via mfma. No per-lane arrays.
__global__ __launch_bounds__(512) void k_stage1m(const unsigned short* __restrict__ Kp,
                                                 const unsigned short* __restrict__ VpT,
                                                 const unsigned short* __restrict__ At,
                                                 float* __restrict__ attn_out,
                                                 float* __restrict__ VVn) {
  __shared__ unsigned short Ks[256 * 64];   // [s][f] swz
  __shared__ unsigned short VTs[64 * 256];  // [f][s] swz
  __shared__ unsigned short Ps[64 * 256];   // [d][s] swz
  __shared__ float mred[512], lred[512], mfin[64], linv[64];
  const int bh = blockIdx.x;
  const int t = threadIdx.x;               // 0..511
  const int w = t >> 6, l = t & 63;
  const int l16 = l & 15, g4 = l >> 4;
  const unsigned short* kg = Kp  + (size_t)bh * 131072;
  const unsigned short* vg = VpT + (size_t)bh * 131072;

  // hoisted B-frags of A^T: B[k=f][n=d] = At[d][f]
  bf16x8 bfr[4][2];
#pragma unroll
  for (int nt = 0; nt < 4; nt++)
#pragma unroll
    for (int ks = 0; ks < 2; ks++)
      bfr[nt][ks] = *(const bf16x8*)&At[(nt * 16 + l16) * 64 + ks * 32 + g4 * 8];

  float m4[4], l4[4];
#pragma unroll
  for (int nt = 0; nt < 4; nt++) { m4[nt] = -1e30f; l4[nt] = 0.f; }

  // ---------------- pass A: online (m,l) per column d ----------------
  for (int st = 0; st < 8; st++) {
    __syncthreads();
#pragma unroll
    for (int i = 0; i < 4; i++) {
      int chunk = t + 512 * i;
      int row = chunk >> 3, fo = (chunk & 7) * 8;
      us8 v = *(const us8*)&kg[(size_t)(st * 256 + row) * 64 + fo];
      *(us8*)&Ks[row * 64 + (((fo * 2) ^ ((row & 7) << 4)) >> 1)] = v;
    }
    __syncthreads();
    f32x4 s_[2][4];
#pragma unroll
    for (int mt = 0; mt < 2; mt++)
#pragma unroll
      for (int nt = 0; nt < 4; nt++) s_[mt][nt] = (f32x4){0.f, 0.f, 0.f, 0.f};
#pragma unroll
    for (int mt = 0; mt < 2; mt++) {
      int ar = w * 32 + mt * 16 + l16;
#pragma unroll
      for (int ks = 0; ks < 2; ks++) {
        bf16x8 af = *(const bf16x8*)&Ks[ar * 64 + (((ks * 64 + g4 * 16) ^ ((ar & 7) << 4)) >> 1)];
#pragma unroll
        for (int nt = 0; nt < 4; nt++)
          s_[mt][nt] = __builtin_amdgcn_mfma_f32_16x16x32_bf16(af, bfr[nt][ks], s_[mt][nt], 0, 0, 0);
      }
    }
#pragma unroll
    for (int nt = 0; nt < 4; nt++) {
      float tm = s_[0][nt][0];
#pragma unroll
      for (int r = 1; r < 4; r++) tm = fmaxf(tm, s_[0][nt][r]);
#pragma unroll
      for (int r = 0; r < 4; r++) tm = fmaxf(tm, s_[1][nt][r]);
      tm *= 0.125f;
      float mn = fmaxf(m4[nt], tm);
      float sum = 0.f;
#pragma unroll
      for (int mt = 0; mt < 2; mt++)
#pragma unroll
        for (int r = 0; r < 4; r++) sum += __expf(s_[mt][nt][r] * 0.125f - mn);
      l4[nt] = l4[nt] * __expf(m4[nt] - mn) + sum;
      m4[nt] = mn;
    }
  }
  // reduce across the 4 row-groups (lanes sharing l16)
#pragma unroll
  for (int nt = 0; nt < 4; nt++) {
#pragma unroll
    for (int off = 16; off < 64; off <<= 1) {
      float m2 = __shfl_xor(m4[nt], off);
      float l2 = __shfl_xor(l4[nt], off);
      float mn = fmaxf(m4[nt], m2);
      l4[nt] = l4[nt] * __expf(m4[nt] - mn) + l2 * __expf(m2 - mn);
      m4[nt] = mn;
    }
  }
  if (l < 16) {
#pragma unroll
    for (int nt = 0; nt < 4; nt++) {
      mred[w * 64 + nt * 16 + l] = m4[nt];
      lred[w * 64 + nt * 16 + l] = l4[nt];
    }
  }
  __syncthreads();
  if (w == 0) {
    float m = -1e30f;
#pragma unroll
    for (int wv = 0; wv < 8; wv++) m = fmaxf(m, mred[wv * 64 + l]);
    float ls = 0.f;
#pragma unroll
    for (int wv = 0; wv < 8; wv++) ls += lred[wv * 64 + l] * __expf(mred[wv * 64 + l] - m);
    mfin[l] = m;
    linv[l] = 1.f / ls;
  }

  // ---------------- pass B: attn out + VV accumulate ----------------
  f32x4 vv[2];
  vv[0] = (f32x4){0.f, 0.f, 0.f, 0.f};
  vv[1] = (f32x4){0.f, 0.f, 0.f, 0.f};
  const int mtv = w & 3, nbase = (w >> 2) * 2;
  float* aout = attn_out + (size_t)bh * 131072;
  for (int st = 0; st < 8; st++) {
    __syncthreads();
#pragma unroll
    for (int i = 0; i < 4; i++) {
      int chunk = t + 512 * i;
      {
        int row = chunk >> 3, fo = (chunk & 7) * 8;
        us8 v = *(const us8*)&kg[(size_t)(st * 256 + row) * 64 + fo];
        *(us8*)&Ks[row * 64 + (((fo * 2) ^ ((row & 7) << 4)) >> 1)] = v;
      }
      {
        int fr = chunk >> 5, so = (chunk & 31) * 8;
        us8 v = *(const us8*)&vg[(size_t)fr * 2048 + st * 256 + so];
        *(us8*)&VTs[fr * 256 + (((so * 2) ^ ((fr & 7) << 4)) >> 1)] = v;
      }
    }
    __syncthreads();
    f32x4 s_[2][4];
#pragma unroll
    for (int mt = 0; mt < 2; mt++)
#pragma unroll
      for (int nt = 0; nt < 4; nt++) s_[mt][nt] = (f32x4){0.f, 0.f, 0.f, 0.f};
#pragma unroll
    for (int mt = 0; mt < 2; mt++) {
      int ar = w * 32 + mt * 16 + l16;
#pragma unroll
      for (int ks = 0; ks < 2; ks++) {
        bf16x8 af = *(const bf16x8*)&Ks[ar * 64 + (((ks * 64 + g4 * 16) ^ ((ar & 7) << 4)) >> 1)];
#pragma unroll
        for (int nt = 0; nt < 4; nt++)
          s_[mt][nt] = __builtin_amdgcn_mfma_f32_16x16x32_bf16(af, bfr[nt][ks], s_[mt][nt], 0, 0, 0);
      }
    }
#pragma unroll
    for (int mt = 0; mt < 2; mt++) {
      int sg = w * 32 + mt * 16 + g4 * 4;
#pragma unroll
      for (int nt = 0; nt < 4; nt++) {
        int d = nt * 16 + l16;
        float mf = mfin[d], il = linv[d];
        f32x4 ev;
#pragma unroll
        for (int r = 0; r < 4; r++) ev[r] = __expf(s_[mt][nt][r] * 0.125f - mf);
        f32x4 av = ev * il;
        *(f32x4*)&aout[(size_t)d * 2048 + st * 256 + sg] = av;
        us4 pb = { f2bf(ev.x), f2bf(ev.y), f2bf(ev.z), f2bf(ev.w) };
        *(us4*)&Ps[d * 256 + (((sg * 2) ^ ((d & 7) << 4)) >> 1)] = pb;
      }
    }
    __syncthreads();
#pragma unroll
    for (int ks = 0; ks < 8; ks++) {
      int ar = mtv * 16 + l16;
      bf16x8 pa = *(const bf16x8*)&Ps[ar * 256 + (((ks * 64 + g4 * 16) ^ ((ar & 7) << 4)) >> 1)];
#pragma unroll
      for (int j = 0; j < 2; j++) {
        int fr = (nbase + j) * 16 + l16;
        bf16x8 vb = *(const bf16x8*)&VTs[fr * 256 + (((ks * 64 + g4 * 16) ^ ((fr & 7) << 4)) >> 1)];
        vv[j] = __builtin_amdgcn_mfma_f32_16x16x32_bf16(pa, vb, vv[j], 0, 0, 0);
      }
    }
  }
#pragma unroll
  for (int j = 0; j < 2; j++)
#pragma unroll
    for (int r = 0; r < 4; r++) {
      int d = mtv * 16 + g4 * 4 + r;
      int f = (nbase + j) * 16 + l16;
      VVn[(size_t)bh * 4096 + d * 64 + f] = vv[j][r] * linv[d];
    }
}

// ---- stage 2 (MFMA): per block = (s-tile of 256, bh). S2 = Q@A^T (softmax over d),
// VVV = P2@VV, scatter-reshape into X. Row-softmax via 16-lane shfl in C-layout; 1 barrier.
__global__ __launch_bounds__(512) void k_stage2m(const unsigned short* __restrict__ Qp,
                                                 const unsigned short* __restrict__ Ab,
                                                 const float* __restrict__ VVn,
                                                 float* __restrict__ X) {
  __shared__ unsigned short Qs[256 * 64];   // [s][f] swz (32 KB)
  __shared__ unsigned short Ps[256 * 64];   // [s][d] swz (32 KB), wave-private rows
  __shared__ unsigned short VVT[64 * 64];   // [f][d] swz (8 KB)
  const int bh = blockIdx.y, b = bh >> 4, h = bh & 15;
  const int stile = blockIdx.x;             // 0..7
  const int t = threadIdx.x;                // 0..511
  const int w = t >> 6, l = t & 63;
  const int l16 = l & 15, g4 = l >> 4;

  // hoisted B-frags of A: B[k=f][n=d] = A[d][f] = Ab[d*64+f]
  bf16x8 abf[4][2];
#pragma unroll
  for (int nt = 0; nt < 4; nt++)
#pragma unroll
    for (int ks = 0; ks < 2; ks++)
      abf[nt][ks] = *(const bf16x8*)&Ab[(nt * 16 + l16) * 64 + ks * 32 + g4 * 8];

  // stage VV^T: VVn[bh][d][f] f32 -> VVT[f][d] bf16 swz
  for (int i = t; i < 4096; i += 512) {
    int d = i >> 6, f = i & 63;
    float v = VVn[(size_t)bh * 4096 + i];
    VVT[f * 64 + (((d * 2) ^ ((f & 7) << 4)) >> 1)] = f2bf(v);
  }
  // stage Q tile: [256][64] swz
  const unsigned short* qg = Qp + (size_t)bh * 131072 + (size_t)stile * 256 * 64;
#pragma unroll
  for (int i = 0; i < 4; i++) {
    int chunk = t + 512 * i;                // 0..2047
    int row = chunk >> 3, fo = (chunk & 7) * 8;
    us8 v = *(const us8*)&qg[row * 64 + fo];
    *(us8*)&Qs[row * 64 + (((fo * 2) ^ ((row & 7) << 4)) >> 1)] = v;
  }
  __syncthreads();

  // scores: S2[s,d], wave w owns rows w*32..w*32+31
  f32x4 s_[2][4];
#pragma unroll
  for (int mt = 0; mt < 2; mt++)
#pragma unroll
    for (int nt = 0; nt < 4; nt++) s_[mt][nt] = (f32x4){0.f, 0.f, 0.f, 0.f};
#pragma unroll
  for (int mt = 0; mt < 2; mt++) {
    int ar = w * 32 + mt * 16 + l16;
#pragma unroll
    for (int ks = 0; ks < 2; ks++) {
      bf16x8 af = *(const bf16x8*)&Qs[ar * 64 + (((ks * 64 + g4 * 16) ^ ((ar & 7) << 4)) >> 1)];
#pragma unroll
      for (int nt = 0; nt < 4; nt++)
        s_[mt][nt] = __builtin_amdgcn_mfma_f32_16x16x32_bf16(af, abf[nt][ks], s_[mt][nt], 0, 0, 0);
    }
  }

  // row softmax over d (nt regs x 16 lanes), then P2 bf16 -> Ps[s][d]
#pragma unroll
  for (int mt = 0; mt < 2; mt++) {
    f32x4 mx;
#pragma unroll
    for (int r = 0; r < 4; r++) {
      float m = s_[mt][0][r];
#pragma unroll
      for (int nt = 1; nt < 4; nt++) m = fmaxf(m, s_[mt][nt][r]);
      mx[r] = m;
    }
#pragma unroll
    for (int off = 1; off < 16; off <<= 1)
#pragma unroll
      for (int r = 0; r < 4; r++) mx[r] = fmaxf(mx[r], __shfl_xor(mx[r], off));
    f32x4 ev[4], sm = (f32x4){0.f, 0.f, 0.f, 0.f};
#pragma unroll
    for (int nt = 0; nt < 4; nt++)
#pragma unroll
      for (int r = 0; r < 4; r++) {
        ev[nt][r] = __expf((s_[mt][nt][r] - mx[r]) * 0.125f);
        sm[r] += ev[nt][r];
      }
#pragma unroll
    for (int off = 1; off < 16; off <<= 1)
#pragma unroll
      for (int r = 0; r < 4; r++) sm[r] += __shfl_xor(sm[r], off);
    f32x4 inv;
#pragma unroll
    for (int r = 0; r < 4; r++) inv[r] = 1.f / sm[r];
#pragma unroll
    for (int nt = 0; nt < 4; nt++)
#pragma unroll
      for (int r = 0; r < 4; r++) {
        int row = w * 32 + mt * 16 + g4 * 4 + r;
        int d = nt * 16 + l16;
        Ps[row * 64 + (((d * 2) ^ ((row & 7) << 4)) >> 1)] = f2bf(ev[nt][r] * inv[r]);
      }
  }
  // PV: wave-private Ps rows -> no block barrier needed (same-wave LDS ordering)
  f32x4 o_[2][4];
#pragma unroll
  for (int mt = 0; mt < 2; mt++)
#pragma unroll
    for (int nt = 0; nt < 4; nt++) o_[mt][nt] = (f32x4){0.f, 0.f, 0.f, 0.f};
#pragma unroll
  for (int mt = 0; mt < 2; mt++) {
    int ar = w * 32 + mt * 16 + l16;
#pragma unroll
    for (int ks = 0; ks < 2; ks++) {
      bf16x8 pa = *(const bf16x8*)&Ps[ar * 64 + (((ks * 64 + g4 * 16) ^ ((ar & 7) << 4)) >> 1)];
#pragma unroll
      for (int nt = 0; nt < 4; nt++) {
        int fr = nt * 16 + l16;
        bf16x8 vb = *(const bf16x8*)&VVT[fr * 64 + (((ks * 64 + g4 * 16) ^ ((fr & 7) << 4)) >> 1)];
        o_[mt][nt] = __builtin_amdgcn_mfma_f32_16x16x32_bf16(pa, vb, o_[mt][nt], 0, 0, 0);
      }
    }
  }
  // scatter into X: row jj = h*128 + s/16, col cc = (s%16)*64 + f
#pragma unroll
  for (int mt = 0; mt < 2; mt++)
#pragma unroll
    for (int nt = 0; nt < 4; nt++)
#pragma unroll
      for (int r = 0; r < 4; r++) {
        int sl = stile * 256 + w * 32 + mt * 16 + g4 * 4 + r;
        int f = nt * 16 + l16;
        int jj = h * 128 + (sl >> 4);
        int cc = (sl & 15) * 64 + f;
        X[((size_t)(b * 2048 + jj)) * 1024 + cc] = o_[mt][nt][r];
      }
}

// ---- residual + LayerNorm; optionally also write bf16 copy ----
template <bool WB>
__global__ __launch_bounds__(256) void k_ln(const float* __restrict__ xa, const float* __restrict__ xb,
                                            const float* __restrict__ g, const float* __restrict__ bbv,
                                            float* __restrict__ outf, unsigned short* __restrict__ outb) {
  __shared__ float red[2][4];
  const size_t row = blockIdx.x;
  const int t = threadIdx.x;
  const int wv = t >> 6, l = t & 63;
  f32x4 va = ((const f32x4*)(xa + row * 1024))[t];
  f32x4 vb = ((const f32x4*)(xb + row * 1024))[t];
  f32x4 v = va + vb;
  float s = v.x + v.y + v.z + v.w;
  float q = v.x * v.x + v.y * v.y + v.z * v.z + v.w * v.w;
#pragma unroll
  for (int o = 1; o < 64; o <<= 1) { s += __shfl_xor(s, o); q += __shfl_xor(q, o); }
  if (l == 0) { red[0][wv] = s; red[1][wv] = q; }
  __syncthreads();
  s = red[0][0] + red[0][1] + red[0][2] + red[0][3];
  q = red[1][0] + red[1][1] + red[1][2] + red[1][3];
  const float mean = s * (1.f / 1024.f);
  const float var = q * (1.f / 1024.f) - mean * mean;
  const float rstd = rsqrtf(var + 1e-5f);
  f32x4 gg = ((const f32x4*)g)[t];
  f32x4 bv = ((const f32x4*)bbv)[t];
  f32x4 o;
  o.x = (v.x - mean) * rstd * gg.x + bv.x;
  o.y = (v.y - mean) * rstd * gg.y + bv.y;
  o.z = (v.z - mean) * rstd * gg.z + bv.z;
  o.w = (v.w - mean) * rstd * gg.w + bv.w;
  ((f32x4*)(outf + row * 1024))[t] = o;
  if (WB) {
    us4 ob = { f2bf(o.x), f2bf(o.y), f2bf(o.z), f2bf(o.w) };
    ((us4*)(outb + row * 1024))[t] = ob;
  }
}

extern "C" void kernel_launch(void* const* d_in, const int* in_sizes, int n_in,
                              void* d_out, int out_size, void* d_ws, size_t ws_size,
                              hipStream_t stream) {
  const float* inQ = (const float*)d_in[0];
  const float* inK = (const float*)d_in[1];
  const float* inV = (const float*)d_in[2];
  const float* Wq1 = (const float*)d_in[3];
  const float* Wq2 = (const float*)d_in[4];
  const float* Wk1 = (const float*)d_in[5];
  const float* Wk2 = (const float*)d_in[6];
  const float* Wv  = (const float*)d_in[7];
  const float* Wfc = (const float*)d_in[8];
  const float* Aw  = (const float*)d_in[9];
  const float* lng = (const float*)d_in[10];
  const float* lnb = (const float*)d_in[11];
  float* out = (float*)d_out;
  float* attn_out = out + (size_t)Mm * Dd;   // output 1: attn_VV [8,16,64,2048]

  char* ws = (char*)d_ws;
  unsigned short* WvT  = (unsigned short*)(ws + 0ull);           //  2 MB
  unsigned short* WfcT = (unsigned short*)(ws + 2097152ull);     //  2 MB
  float* Qmid          = (float*)(ws + 4194304ull);              //  2 MB (-> At/Ab bf16 after qkexpand)
  float* Kmid          = (float*)(ws + 6291456ull);              //  2 MB
  unsigned short* Qp   = (unsigned short*)(ws + 8388608ull);     // 32 MB
  unsigned short* Kp   = (unsigned short*)(ws + 41943040ull);    // 32 MB -> later o1 bf16
  unsigned short* KpT  = (unsigned short*)(ws + 75497472ull);    // (unused) -> o2 (64 MB f32)
  unsigned short* VpT  = (unsigned short*)(ws + 109051904ull);   // 32 MB
  unsigned short* Vbf  = (unsigned short*)(ws + 142606336ull);   // 32 MB -> later X / o1f (64 MB f32)
  unsigned short* Vp   = (unsigned short*)(ws + 176160768ull);   // 32 MB
  float* VVn           = (float*)(ws + 209715200ull);            //  2 MB
  unsigned short* Atb = (unsigned short*)(ws + 4194304ull);      // 8 KB, reuses Qmid region
  unsigned short* A2b = (unsigned short*)(ws + 4194304ull + 8192ull); // 8 KB
  float* o2  = (float*)(ws + 75497472ull);
  float* X   = (float*)(ws + 142606336ull);
  float* o1f = X;
  unsigned short* o1b = Kp;
  (void)KpT;

  k_transpose_w<<<dim3(32, 32), 256, 0, stream>>>(Wv, WvT);
  k_transpose_w<<<dim3(32, 32), 256, 0, stream>>>(Wfc, WfcT);
  k_cvt<<<dim3(4096), 256, 0, stream>>>(inV, Vbf);
  k_qkmid<<<dim3(2048, 2), 256, 0, stream>>>(inQ, inK, Wq1, Wk1, Qmid, Kmid);
  k_qkexpand<<<dim3(1024, 2), 256, 0, stream>>>(Qmid, Kmid, Wq2, Wk2, Qp, Kp);
  k_prep_at<<<dim3(16), 256, 0, stream>>>(Aw, Atb, A2b);
  k_gemm<0><<<dim3(8, 128), 256, 0, stream>>>(Vbf, WvT, (void*)Vp);
  k_transpose_bh<<<dim3(32, 128), 256, 0, stream>>>(Vp, VpT);
  k_stage1m<<<dim3(128), 512, 0, stream>>>(Kp, VpT, Atb, attn_out, VVn);
  k_stage2m<<<dim3(8, 128), 512, 0, stream>>>(Qp, A2b, VVn, X);
  k_ln<true><<<dim3(16384), 256, 0, stream>>>(X, inQ, lng, lnb, o1f, o1b);
  k_gemm<1><<<dim3(8, 128), 256, 0, stream>>>(o1b, WfcT, (void*)o2);
  k_ln<false><<<dim3(16384), 256, 0, stream>>>(o2, o1f, lng, lnb, out, nullptr);
}

// Round 5
// 715.885 us; speedup vs baseline: 3.5027x; 1.0922x over previous
//
#include <hip/hip_runtime.h>
#include <hip/hip_bf16.h>
#include <stdint.h>

typedef __attribute__((ext_vector_type(4))) float f32x4;
typedef __attribute__((ext_vector_type(8))) short bf16x8;
typedef __attribute__((ext_vector_type(4))) unsigned short us4;
typedef __attribute__((ext_vector_type(8))) unsigned short us8;

static constexpr int Bb = 8, Ss = 2048, Dd = 1024, Hh = 16, DHh = 64;
static constexpr int Mm = Bb * Ss;   // 16384
#define DEVI static __device__ __forceinline__

DEVI float bf2f(unsigned short u) {
  union { unsigned int i; float f; } v; v.i = ((unsigned int)u) << 16; return v.f;
}
DEVI unsigned short f2bf(float f) {
  union { float f; unsigned int i; } v; v.f = f;
  unsigned int r = v.i + 0x7FFFu + ((v.i >> 16) & 1u);
  return (unsigned short)(r >> 16);
}

// ---- W [K=1024][N=1024] f32 -> WT bf16 [N][K] ----
__global__ __launch_bounds__(256) void k_transpose_w(const float* __restrict__ W,
                                                     unsigned short* __restrict__ WT) {
  __shared__ float tile[32][33];
  const int n0 = blockIdx.x * 32, k0 = blockIdx.y * 32;
  const int t = threadIdx.x, tr = t >> 5, tc = t & 31;
#pragma unroll
  for (int i = 0; i < 4; i++) {
    int r = tr + 8 * i;
    tile[r][tc] = W[(size_t)(k0 + r) * 1024 + n0 + tc];
  }
  __syncthreads();
#pragma unroll
  for (int i = 0; i < 4; i++) {
    int r = tr + 8 * i;
    WT[(size_t)(n0 + r) * 1024 + k0 + tc] = f2bf(tile[tc][r]);
  }
}

// ---- Weff^T[n][k] bf16 = sum_j W1[k][j] * W2[j][n]  (W1 [1024][32], W2 [32][1024]) ----
__global__ __launch_bounds__(256) void k_weff(const float* __restrict__ W1, const float* __restrict__ W2,
                                              unsigned short* __restrict__ WT) {
  __shared__ float s1[64][33];   // padded: compute reads column j across kL lanes
  __shared__ float s2[32][64];
  const int n0 = blockIdx.x * 64, k0 = blockIdx.y * 64;
  const int t = threadIdx.x;
#pragma unroll
  for (int u = 0; u < 8; u++) {
    int e = t * 8 + u;                       // 0..2047, contiguous over W1 tile
    s1[e >> 5][e & 31] = W1[k0 * 32 + e];
  }
  {
    int e = t * 8;                           // j = e>>6, nl = e&63
    const f32x4* src = (const f32x4*)&W2[(size_t)(e >> 6) * 1024 + n0 + (e & 63)];
    *(f32x4*)&s2[e >> 6][e & 63] = src[0];
    *(f32x4*)&s2[e >> 6][(e & 63) + 4] = src[1];
  }
  __syncthreads();
  const int g = t >> 6, kL = t & 63;
#pragma unroll
  for (int i = 0; i < 16; i++) {
    int nL = g * 16 + i;
    float acc = 0.f;
#pragma unroll
    for (int j = 0; j < 32; j++) acc += s1[kL][j] * s2[j][nL];
    WT[(size_t)(n0 + nL) * 1024 + k0 + kL] = f2bf(acc);
  }
}

// ---- f32 -> bf16 elementwise (16M elements) ----
__global__ __launch_bounds__(256) void k_cvt(const float* __restrict__ x,
                                             unsigned short* __restrict__ y) {
  const int n4 = (Mm * Dd) / 4;
  for (int i = blockIdx.x * 256 + threadIdx.x; i < n4; i += gridDim.x * 256) {
    f32x4 v = ((const f32x4*)x)[i];
    us4 o = { f2bf(v.x), f2bf(v.y), f2bf(v.z), f2bf(v.w) };
    ((us4*)y)[i] = o;
  }
}

// ---- A[f][d] f32 -> At[d][f] bf16 (transposed, stage1) + Ab bf16 straight (stage2) ----
__global__ __launch_bounds__(256) void k_prep_at(const float* __restrict__ A,
                                                 unsigned short* __restrict__ At,
                                                 unsigned short* __restrict__ Ab) {
  int t = blockIdx.x * 256 + threadIdx.x;   // 0..4095
  int d = t >> 6, f = t & 63;
  At[d * 64 + f] = f2bf(A[f * 64 + d]);
  Ab[t] = f2bf(A[t]);
}

// ---- per-(b,h) transpose: [2048][64] bf16 -> [64][2048] bf16 ----
__global__ __launch_bounds__(256) void k_transpose_bh(const unsigned short* __restrict__ src,
                                                      unsigned short* __restrict__ dst) {
  __shared__ unsigned short tile[64][72];
  const int bh = blockIdx.y, s0 = blockIdx.x * 64;
  const int t = threadIdx.x;
  {
    int sl = t >> 2, fc = (t & 3) * 16;
    const unsigned short* sp = src + ((size_t)bh * 2048 + s0 + sl) * 64 + fc;
    *(us8*)&tile[sl][fc]     = *(const us8*)sp;
    *(us8*)&tile[sl][fc + 8] = *(const us8*)(sp + 8);
  }
  __syncthreads();
  {
    int f = t >> 2, sc = (t & 3) * 16;
    unsigned short* dp = dst + ((size_t)bh * 64 + f) * 2048 + s0 + sc;
    us8 a, bq;
#pragma unroll
    for (int i = 0; i < 8; i++) a[i] = tile[sc + i][f];
#pragma unroll
    for (int i = 0; i < 8; i++) bq[i] = tile[sc + 8 + i][f];
    *(us8*)dp = a;
    *(us8*)(dp + 8) = bq;
  }
}

// ---- bf16 MFMA GEMM: A[M,1024] bf16 @ (BT[N,1024])^T, 128x128 tile, BK=64 ----
template <int EPI>
__global__ __launch_bounds__(256) void k_gemm(const unsigned short* __restrict__ Ag,
                                              const unsigned short* __restrict__ BTg,
                                              void* __restrict__ Cout) {
  __shared__ unsigned short As[128 * 64];
  __shared__ unsigned short Bs[128 * 64];
  const int m0 = blockIdx.y * 128, n0 = blockIdx.x * 128;
  const int t = threadIdx.x;
  const int w = t >> 6, l = t & 63;
  const int wr = w >> 1, wc = w & 1;
  const int g4 = l >> 4, l16 = l & 15;
  f32x4 acc[4][4];
#pragma unroll
  for (int i = 0; i < 4; i++)
#pragma unroll
    for (int jj = 0; jj < 4; jj++) acc[i][jj] = (f32x4){0.f, 0.f, 0.f, 0.f};

  const int srow = t >> 1, shalf = (t & 1) * 32;
  const us8* ga = (const us8*)(Ag  + (size_t)(m0 + srow) * 1024 + shalf);
  const us8* gb = (const us8*)(BTg + (size_t)(n0 + srow) * 1024 + shalf);
  const int swz = (srow & 7) << 4;
#pragma unroll 1
  for (int kt = 0; kt < 16; kt++) {
    __syncthreads();
#pragma unroll
    for (int c = 0; c < 4; c++) {
      int kb = (shalf + c * 8) * 2;
      *(us8*)&As[srow * 64 + ((kb ^ swz) >> 1)] = ga[c];
      *(us8*)&Bs[srow * 64 + ((kb ^ swz) >> 1)] = gb[c];
    }
    ga += 8; gb += 8;
    __syncthreads();
#pragma unroll
    for (int kk = 0; kk < 64; kk += 32) {
      bf16x8 af[4], bfr[4];
      const int kbyte = (kk + 8 * g4) * 2;
#pragma unroll
      for (int mt = 0; mt < 4; mt++) {
        int row = wr * 64 + mt * 16 + l16;
        af[mt] = *(const bf16x8*)&As[row * 64 + ((kbyte ^ ((row & 7) << 4)) >> 1)];
      }
#pragma unroll
      for (int nt = 0; nt < 4; nt++) {
        int row = wc * 64 + nt * 16 + l16;
        bfr[nt] = *(const bf16x8*)&Bs[row * 64 + ((kbyte ^ ((row & 7) << 4)) >> 1)];
      }
#pragma unroll
      for (int mt = 0; mt < 4; mt++)
#pragma unroll
        for (int nt = 0; nt < 4; nt++)
          acc[mt][nt] = __builtin_amdgcn_mfma_f32_16x16x32_bf16(af[mt], bfr[nt], acc[mt][nt], 0, 0, 0);
    }
  }
#pragma unroll
  for (int mt = 0; mt < 4; mt++)
#pragma unroll
    for (int nt = 0; nt < 4; nt++)
#pragma unroll
      for (int r = 0; r < 4; r++) {
        int m = m0 + wr * 64 + mt * 16 + g4 * 4 + r;
        int n = n0 + wc * 64 + nt * 16 + l16;
        float v = acc[mt][nt][r];
        if (EPI == 0) {
          int b = m >> 11, s = m & 2047, h = n >> 6, f = n & 63;
          ((unsigned short*)Cout)[(((size_t)(b * 16 + h) * 2048) + s) * 64 + f] = f2bf(v);
        } else {
          ((float*)Cout)[(size_t)m * 1024 + n] = v;
        }
      }
}

// ---- stage 1 (MFMA): per block = one (b,h). S = K@At^T via mfma, online softmax over s,
// pass B: attn = e*invl -> global, P(bf16)->LDS, VV += P@V via mfma. No per-lane arrays.
__global__ __launch_bounds__(512) void k_stage1m(const unsigned short* __restrict__ Kp,
                                                 const unsigned short* __restrict__ VpT,
                                                 const unsigned short* __restrict__ At,
                                                 float* __restrict__ attn_out,
                                                 float* __restrict__ VVn) {
  __shared__ unsigned short Ks[256 * 64];   // [s][f] swz
  __shared__ unsigned short VTs[64 * 256];  // [f][s] swz
  __shared__ unsigned short Ps[64 * 256];   // [d][s] swz
  __shared__ float mred[512], lred[512], mfin[64], linv[64];
  const int bh = blockIdx.x;
  const int t = threadIdx.x;               // 0..511
  const int w = t >> 6, l = t & 63;
  const int l16 = l & 15, g4 = l >> 4;
  const unsigned short* kg = Kp  + (size_t)bh * 131072;
  const unsigned short* vg = VpT + (size_t)bh * 131072;

  // hoisted B-frags of A^T: B[k=f][n=d] = At[d][f]
  bf16x8 bfr[4][2];
#pragma unroll
  for (int nt = 0; nt < 4; nt++)
#pragma unroll
    for (int ks = 0; ks < 2; ks++)
      bfr[nt][ks] = *(const bf16x8*)&At[(nt * 16 + l16) * 64 + ks * 32 + g4 * 8];

  float m4[4], l4[4];
#pragma unroll
  for (int nt = 0; nt < 4; nt++) { m4[nt] = -1e30f; l4[nt] = 0.f; }

  // ---------------- pass A: online (m,l) per column d ----------------
  for (int st = 0; st < 8; st++) {
    __syncthreads();
#pragma unroll
    for (int i = 0; i < 4; i++) {
      int chunk = t + 512 * i;
      int row = chunk >> 3, fo = (chunk & 7) * 8;
      us8 v = *(const us8*)&kg[(size_t)(st * 256 + row) * 64 + fo];
      *(us8*)&Ks[row * 64 + (((fo * 2) ^ ((row & 7) << 4)) >> 1)] = v;
    }
    __syncthreads();
    f32x4 s_[2][4];
#pragma unroll
    for (int mt = 0; mt < 2; mt++)
#pragma unroll
      for (int nt = 0; nt < 4; nt++) s_[mt][nt] = (f32x4){0.f, 0.f, 0.f, 0.f};
#pragma unroll
    for (int mt = 0; mt < 2; mt++) {
      int ar = w * 32 + mt * 16 + l16;
#pragma unroll
      for (int ks = 0; ks < 2; ks++) {
        bf16x8 af = *(const bf16x8*)&Ks[ar * 64 + (((ks * 64 + g4 * 16) ^ ((ar & 7) << 4)) >> 1)];
#pragma unroll
        for (int nt = 0; nt < 4; nt++)
          s_[mt][nt] = __builtin_amdgcn_mfma_f32_16x16x32_bf16(af, bfr[nt][ks], s_[mt][nt], 0, 0, 0);
      }
    }
#pragma unroll
    for (int nt = 0; nt < 4; nt++) {
      float tm = s_[0][nt][0];
#pragma unroll
      for (int r = 1; r < 4; r++) tm = fmaxf(tm, s_[0][nt][r]);
#pragma unroll
      for (int r = 0; r < 4; r++) tm = fmaxf(tm, s_[1][nt][r]);
      tm *= 0.125f;
      float mn = fmaxf(m4[nt], tm);
      float sum = 0.f;
#pragma unroll
      for (int mt = 0; mt < 2; mt++)
#pragma unroll
        for (int r = 0; r < 4; r++) sum += __expf(s_[mt][nt][r] * 0.125f - mn);
      l4[nt] = l4[nt] * __expf(m4[nt] - mn) + sum;
      m4[nt] = mn;
    }
  }
  // reduce across the 4 row-groups (lanes sharing l16)
#pragma unroll
  for (int nt = 0; nt < 4; nt++) {
#pragma unroll
    for (int off = 16; off < 64; off <<= 1) {
      float m2 = __shfl_xor(m4[nt], off);
      float l2 = __shfl_xor(l4[nt], off);
      float mn = fmaxf(m4[nt], m2);
      l4[nt] = l4[nt] * __expf(m4[nt] - mn) + l2 * __expf(m2 - mn);
      m4[nt] = mn;
    }
  }
  if (l < 16) {
#pragma unroll
    for (int nt = 0; nt < 4; nt++) {
      mred[w * 64 + nt * 16 + l] = m4[nt];
      lred[w * 64 + nt * 16 + l] = l4[nt];
    }
  }
  __syncthreads();
  if (w == 0) {
    float m = -1e30f;
#pragma unroll
    for (int wv = 0; wv < 8; wv++) m = fmaxf(m, mred[wv * 64 + l]);
    float ls = 0.f;
#pragma unroll
    for (int wv = 0; wv < 8; wv++) ls += lred[wv * 64 + l] * __expf(mred[wv * 64 + l] - m);
    mfin[l] = m;
    linv[l] = 1.f / ls;
  }

  // ---------------- pass B: attn out + VV accumulate ----------------
  f32x4 vv[2];
  vv[0] = (f32x4){0.f, 0.f, 0.f, 0.f};
  vv[1] = (f32x4){0.f, 0.f, 0.f, 0.f};
  const int mtv = w & 3, nbase = (w >> 2) * 2;
  float* aout = attn_out + (size_t)bh * 131072;
  for (int st = 0; st < 8; st++) {
    __syncthreads();
#pragma unroll
    for (int i = 0; i < 4; i++) {
      int chunk = t + 512 * i;
      {
        int row = chunk >> 3, fo = (chunk & 7) * 8;
        us8 v = *(const us8*)&kg[(size_t)(st * 256 + row) * 64 + fo];
        *(us8*)&Ks[row * 64 + (((fo * 2) ^ ((row & 7) << 4)) >> 1)] = v;
      }
      {
        int fr = chunk >> 5, so = (chunk & 31) * 8;
        us8 v = *(const us8*)&vg[(size_t)fr * 2048 + st * 256 + so];
        *(us8*)&VTs[fr * 256 + (((so * 2) ^ ((fr & 7) << 4)) >> 1)] = v;
      }
    }
    __syncthreads();
    f32x4 s_[2][4];
#pragma unroll
    for (int mt = 0; mt < 2; mt++)
#pragma unroll
      for (int nt = 0; nt < 4; nt++) s_[mt][nt] = (f32x4){0.f, 0.f, 0.f, 0.f};
#pragma unroll
    for (int mt = 0; mt < 2; mt++) {
      int ar = w * 32 + mt * 16 + l16;
#pragma unroll
      for (int ks = 0; ks < 2; ks++) {
        bf16x8 af = *(const bf16x8*)&Ks[ar * 64 + (((ks * 64 + g4 * 16) ^ ((ar & 7) << 4)) >> 1)];
#pragma unroll
        for (int nt = 0; nt < 4; nt++)
          s_[mt][nt] = __builtin_amdgcn_mfma_f32_16x16x32_bf16(af, bfr[nt][ks], s_[mt][nt], 0, 0, 0);
      }
    }
#pragma unroll
    for (int mt = 0; mt < 2; mt++) {
      int sg = w * 32 + mt * 16 + g4 * 4;
#pragma unroll
      for (int nt = 0; nt < 4; nt++) {
        int d = nt * 16 + l16;
        float mf = mfin[d], il = linv[d];
        f32x4 ev;
#pragma unroll
        for (int r = 0; r < 4; r++) ev[r] = __expf(s_[mt][nt][r] * 0.125f - mf);
        f32x4 av = ev * il;
        *(f32x4*)&aout[(size_t)d * 2048 + st * 256 + sg] = av;
        us4 pb = { f2bf(ev.x), f2bf(ev.y), f2bf(ev.z), f2bf(ev.w) };
        *(us4*)&Ps[d * 256 + (((sg * 2) ^ ((d & 7) << 4)) >> 1)] = pb;
      }
    }
    __syncthreads();
#pragma unroll
    for (int ks = 0; ks < 8; ks++) {
      int ar = mtv * 16 + l16;
      bf16x8 pa = *(const bf16x8*)&Ps[ar * 256 + (((ks * 64 + g4 * 16) ^ ((ar & 7) << 4)) >> 1)];
#pragma unroll
      for (int j = 0; j < 2; j++) {
        int fr = (nbase + j) * 16 + l16;
        bf16x8 vb = *(const bf16x8*)&VTs[fr * 256 + (((ks * 64 + g4 * 16) ^ ((fr & 7) << 4)) >> 1)];
        vv[j] = __builtin_amdgcn_mfma_f32_16x16x32_bf16(pa, vb, vv[j], 0, 0, 0);
      }
    }
  }
#pragma unroll
  for (int j = 0; j < 2; j++)
#pragma unroll
    for (int r = 0; r < 4; r++) {
      int d = mtv * 16 + g4 * 4 + r;
      int f = (nbase + j) * 16 + l16;
      VVn[(size_t)bh * 4096 + d * 64 + f] = vv[j][r] * linv[d];
    }
}

// ---- stage 2 (MFMA): per block = (s-tile of 256, bh). S2 = Q@A^T (softmax over d),
// VVV = P2@VV, scatter-reshape into X. Row-softmax via 16-lane shfl in C-layout; 1 barrier.
__global__ __launch_bounds__(512) void k_stage2m(const unsigned short* __restrict__ Qp,
                                                 const unsigned short* __restrict__ Ab,
                                                 const float* __restrict__ VVn,
                                                 float* __restrict__ X) {
  __shared__ unsigned short Qs[256 * 64];   // [s][f] swz (32 KB)
  __shared__ unsigned short Ps[256 * 64];   // [s][d] swz (32 KB), wave-private rows
  __shared__ unsigned short VVT[64 * 64];   // [f][d] swz (8 KB)
  const int bh = blockIdx.y, b = bh >> 4, h = bh & 15;
  const int stile = blockIdx.x;             // 0..7
  const int t = threadIdx.x;                // 0..511
  const int w = t >> 6, l = t & 63;
  const int l16 = l & 15, g4 = l >> 4;

  // hoisted B-frags of A: B[k=f][n=d] = A[d][f] = Ab[d*64+f]
  bf16x8 abf[4][2];
#pragma unroll
  for (int nt = 0; nt < 4; nt++)
#pragma unroll
    for (int ks = 0; ks < 2; ks++)
      abf[nt][ks] = *(const bf16x8*)&Ab[(nt * 16 + l16) * 64 + ks * 32 + g4 * 8];

  // stage VV^T: VVn[bh][d][f] f32 -> VVT[f][d] bf16 swz
  for (int i = t; i < 4096; i += 512) {
    int d = i >> 6, f = i & 63;
    float v = VVn[(size_t)bh * 4096 + i];
    VVT[f * 64 + (((d * 2) ^ ((f & 7) << 4)) >> 1)] = f2bf(v);
  }
  // stage Q tile: [256][64] swz
  const unsigned short* qg = Qp + (size_t)bh * 131072 + (size_t)stile * 256 * 64;
#pragma unroll
  for (int i = 0; i < 4; i++) {
    int chunk = t + 512 * i;                // 0..2047
    int row = chunk >> 3, fo = (chunk & 7) * 8;
    us8 v = *(const us8*)&qg[row * 64 + fo];
    *(us8*)&Qs[row * 64 + (((fo * 2) ^ ((row & 7) << 4)) >> 1)] = v;
  }
  __syncthreads();

  // scores: S2[s,d], wave w owns rows w*32..w*32+31
  f32x4 s_[2][4];
#pragma unroll
  for (int mt = 0; mt < 2; mt++)
#pragma unroll
    for (int nt = 0; nt < 4; nt++) s_[mt][nt] = (f32x4){0.f, 0.f, 0.f, 0.f};
#pragma unroll
  for (int mt = 0; mt < 2; mt++) {
    int ar = w * 32 + mt * 16 + l16;
#pragma unroll
    for (int ks = 0; ks < 2; ks++) {
      bf16x8 af = *(const bf16x8*)&Qs[ar * 64 + (((ks * 64 + g4 * 16) ^ ((ar & 7) << 4)) >> 1)];
#pragma unroll
      for (int nt = 0; nt < 4; nt++)
        s_[mt][nt] = __builtin_amdgcn_mfma_f32_16x16x32_bf16(af, abf[nt][ks], s_[mt][nt], 0, 0, 0);
    }
  }

  // row softmax over d (nt regs x 16 lanes), then P2 bf16 -> Ps[s][d]
#pragma unroll
  for (int mt = 0; mt < 2; mt++) {
    f32x4 mx;
#pragma unroll
    for (int r = 0; r < 4; r++) {
      float m = s_[mt][0][r];
#pragma unroll
      for (int nt = 1; nt < 4; nt++) m = fmaxf(m, s_[mt][nt][r]);
      mx[r] = m;
    }
#pragma unroll
    for (int off = 1; off < 16; off <<= 1)
#pragma unroll
      for (int r = 0; r < 4; r++) mx[r] = fmaxf(mx[r], __shfl_xor(mx[r], off));
    f32x4 ev[4], sm = (f32x4){0.f, 0.f, 0.f, 0.f};
#pragma unroll
    for (int nt = 0; nt < 4; nt++)
#pragma unroll
      for (int r = 0; r < 4; r++) {
        ev[nt][r] = __expf((s_[mt][nt][r] - mx[r]) * 0.125f);
        sm[r] += ev[nt][r];
      }
#pragma unroll
    for (int off = 1; off < 16; off <<= 1)
#pragma unroll
      for (int r = 0; r < 4; r++) sm[r] += __shfl_xor(sm[r], off);
    f32x4 inv;
#pragma unroll
    for (int r = 0; r < 4; r++) inv[r] = 1.f / sm[r];
#pragma unroll
    for (int nt = 0; nt < 4; nt++)
#pragma unroll
      for (int r = 0; r < 4; r++) {
        int row = w * 32 + mt * 16 + g4 * 4 + r;
        int d = nt * 16 + l16;
        Ps[row * 64 + (((d * 2) ^ ((row & 7) << 4)) >> 1)] = f2bf(ev[nt][r] * inv[r]);
      }
  }
  // PV: wave-private Ps rows -> no block barrier needed (same-wave LDS ordering)
  f32x4 o_[2][4];
#pragma unroll
  for (int mt = 0; mt < 2; mt++)
#pragma unroll
    for (int nt = 0; nt < 4; nt++) o_[mt][nt] = (f32x4){0.f, 0.f, 0.f, 0.f};
#pragma unroll
  for (int mt = 0; mt < 2; mt++) {
    int ar = w * 32 + mt * 16 + l16;
#pragma unroll
    for (int ks = 0; ks < 2; ks++) {
      bf16x8 pa = *(const bf16x8*)&Ps[ar * 64 + (((ks * 64 + g4 * 16) ^ ((ar & 7) << 4)) >> 1)];
#pragma unroll
      for (int nt = 0; nt < 4; nt++) {
        int fr = nt * 16 + l16;
        bf16x8 vb = *(const bf16x8*)&VVT[fr * 64 + (((ks * 64 + g4 * 16) ^ ((fr & 7) << 4)) >> 1)];
        o_[mt][nt] = __builtin_amdgcn_mfma_f32_16x16x32_bf16(pa, vb, o_[mt][nt], 0, 0, 0);
      }
    }
  }
  // scatter into X: row jj = h*128 + s/16, col cc = (s%16)*64 + f
#pragma unroll
  for (int mt = 0; mt < 2; mt++)
#pragma unroll
    for (int nt = 0; nt < 4; nt++)
#pragma unroll
      for (int r = 0; r < 4; r++) {
        int sl = stile * 256 + w * 32 + mt * 16 + g4 * 4 + r;
        int f = nt * 16 + l16;
        int jj = h * 128 + (sl >> 4);
        int cc = (sl & 15) * 64 + f;
        X[((size_t)(b * 2048 + jj)) * 1024 + cc] = o_[mt][nt][r];
      }
}

// ---- residual + LayerNorm; optionally also write bf16 copy ----
template <bool WB>
__global__ __launch_bounds__(256) void k_ln(const float* __restrict__ xa, const float* __restrict__ xb,
                                            const float* __restrict__ g, const float* __restrict__ bbv,
                                            float* __restrict__ outf, unsigned short* __restrict__ outb) {
  __shared__ float red[2][4];
  const size_t row = blockIdx.x;
  const int t = threadIdx.x;
  const int wv = t >> 6, l = t & 63;
  f32x4 va = ((const f32x4*)(xa + row * 1024))[t];
  f32x4 vb = ((const f32x4*)(xb + row * 1024))[t];
  f32x4 v = va + vb;
  float s = v.x + v.y + v.z + v.w;
  float q = v.x * v.x + v.y * v.y + v.z * v.z + v.w * v.w;
#pragma unroll
  for (int o = 1; o < 64; o <<= 1) { s += __shfl_xor(s, o); q += __shfl_xor(q, o); }
  if (l == 0) { red[0][wv] = s; red[1][wv] = q; }
  __syncthreads();
  s = red[0][0] + red[0][1] + red[0][2] + red[0][3];
  q = red[1][0] + red[1][1] + red[1][2] + red[1][3];
  const float mean = s * (1.f / 1024.f);
  const float var = q * (1.f / 1024.f) - mean * mean;
  const float rstd = rsqrtf(var + 1e-5f);
  f32x4 gg = ((const f32x4*)g)[t];
  f32x4 bv = ((const f32x4*)bbv)[t];
  f32x4 o;
  o.x = (v.x - mean) * rstd * gg.x + bv.x;
  o.y = (v.y - mean) * rstd * gg.y + bv.y;
  o.z = (v.z - mean) * rstd * gg.z + bv.z;
  o.w = (v.w - mean) * rstd * gg.w + bv.w;
  ((f32x4*)(outf + row * 1024))[t] = o;
  if (WB) {
    us4 ob = { f2bf(o.x), f2bf(o.y), f2bf(o.z), f2bf(o.w) };
    ((us4*)(outb + row * 1024))[t] = ob;
  }
}

extern "C" void kernel_launch(void* const* d_in, const int* in_sizes, int n_in,
                              void* d_out, int out_size, void* d_ws, size_t ws_size,
                              hipStream_t stream) {
  const float* inQ = (const float*)d_in[0];
  const float* inK = (const float*)d_in[1];
  const float* inV = (const float*)d_in[2];
  const float* Wq1 = (const float*)d_in[3];
  const float* Wq2 = (const float*)d_in[4];
  const float* Wk1 = (const float*)d_in[5];
  const float* Wk2 = (const float*)d_in[6];
  const float* Wv  = (const float*)d_in[7];
  const float* Wfc = (const float*)d_in[8];
  const float* Aw  = (const float*)d_in[9];
  const float* lng = (const float*)d_in[10];
  const float* lnb = (const float*)d_in[11];
  float* out = (float*)d_out;
  float* attn_out = out + (size_t)Mm * Dd;   // output 1: attn_VV [8,16,64,2048]

  char* ws = (char*)d_ws;
  // layout (bytes), total 211,812,352 — lifetime-safe aliasing:
  unsigned short* WvT    = (unsigned short*)(ws + 0ull);           // 2 MB
  unsigned short* WfcT   = (unsigned short*)(ws + 2097152ull);     // 2 MB
  unsigned short* WeffqT = (unsigned short*)(ws + 4194304ull);     // 2 MB
  unsigned short* WeffkT = (unsigned short*)(ws + 6291456ull);     // 2 MB
  unsigned short* Qp     = (unsigned short*)(ws + 8388608ull);     // 32 MB
  unsigned short* Kp     = (unsigned short*)(ws + 41943040ull);    // 32 MB -> later o1 bf16
  float* o2              = (float*)(ws + 75497472ull);             // 64 MB (written late)
  unsigned short* Atb    = (unsigned short*)(ws + 75497472ull);    // 8 KB  (dead before o2 written)
  unsigned short* A2b    = (unsigned short*)(ws + 75497472ull + 8192ull); // 8 KB
  unsigned short* VpT    = (unsigned short*)(ws + 109051904ull);   // 32 MB
  unsigned short* Vbf    = (unsigned short*)(ws + 142606336ull);   // 32 MB -> Qbf -> X/o1f (64 MB)
  unsigned short* Qbf    = (unsigned short*)(ws + 142606336ull);
  float* X               = (float*)(ws + 142606336ull);
  float* o1f             = X;
  unsigned short* Vp     = (unsigned short*)(ws + 176160768ull);   // 32 MB -> Kbf (dead before X)
  unsigned short* Kbf    = (unsigned short*)(ws + 176160768ull);
  float* VVn             = (float*)(ws + 209715200ull);            // 2 MB
  unsigned short* o1b    = Kp;

  k_transpose_w<<<dim3(32, 32), 256, 0, stream>>>(Wv, WvT);
  k_transpose_w<<<dim3(32, 32), 256, 0, stream>>>(Wfc, WfcT);
  k_weff<<<dim3(16, 16), 256, 0, stream>>>(Wq1, Wq2, WeffqT);
  k_weff<<<dim3(16, 16), 256, 0, stream>>>(Wk1, Wk2, WeffkT);
  k_prep_at<<<dim3(16), 256, 0, stream>>>(Aw, Atb, A2b);
  k_cvt<<<dim3(4096), 256, 0, stream>>>(inV, Vbf);
  k_gemm<0><<<dim3(8, 128), 256, 0, stream>>>(Vbf, WvT, (void*)Vp);
  k_transpose_bh<<<dim3(32, 128), 256, 0, stream>>>(Vp, VpT);
  k_cvt<<<dim3(4096), 256, 0, stream>>>(inQ, Qbf);
  k_cvt<<<dim3(4096), 256, 0, stream>>>(inK, Kbf);
  k_gemm<0><<<dim3(8, 128), 256, 0, stream>>>(Qbf, WeffqT, (void*)Qp);
  k_gemm<0><<<dim3(8, 128), 256, 0, stream>>>(Kbf, WeffkT, (void*)Kp);
  k_stage1m<<<dim3(128), 512, 0, stream>>>(Kp, VpT, Atb, attn_out, VVn);
  k_stage2m<<<dim3(8, 128), 512, 0, stream>>>(Qp, A2b, VVn, X);
  k_ln<true><<<dim3(16384), 256, 0, stream>>>(X, inQ, lng, lnb, o1f, o1b);
  k_gemm<1><<<dim3(8, 128), 256, 0, stream>>>(o1b, WfcT, (void*)o2);
  k_ln<false><<<dim3(16384), 256, 0, stream>>>(o2, o1f, lng, lnb, out, nullptr);
}